// Round 8
// baseline (828.099 us; speedup 1.0000x reference)
//
#include <hip/hip_runtime.h>

#define NN      100000
#define MHE     200000
#define EE      2000000
#define H1      400000      // hedge keys (2 types)
#define H2      200000      // node keys (2 types)
#define NBK1    782         // ceil(H1/512)
#define NBK2    391         // ceil(H2/512)
#define NGB     1173        // NBK1+NBK2
#define NCB     1024        // counting blocks
#define CHK     1954        // edges per counting block

typedef unsigned short u16;
typedef unsigned int   u32;
typedef unsigned long long ull;
typedef __attribute__((ext_vector_type(8))) short  s16x8;
typedef __attribute__((ext_vector_type(4))) float  f32x4;
typedef __attribute__((ext_vector_type(4))) unsigned int u32x4;

__device__ __forceinline__ float bf2f(u16 u) { return __uint_as_float(((u32)u) << 16); }
__device__ __forceinline__ u16 f2bf(float f) {
    u32 u = __float_as_uint(f);
    return (u16)((u + 0x7fffu + ((u >> 16) & 1u)) >> 16);
}
__device__ __forceinline__ float ldv(const void* p, long i, int isf32) {
    return isf32 ? ((const float*)p)[i] : bf2f(((const u16*)p)[i]);
}
__device__ __forceinline__ u16 ldb(const void* p, long i, int isf32) {
    return isf32 ? f2bf(((const float*)p)[i]) : ((const u16*)p)[i];
}
__device__ __forceinline__ void stv(void* p, long i, float v, int isf32) {
    if (isf32) ((float*)p)[i] = v;
    else       ((u16*)p)[i] = f2bf(v);
}

union FragU { s16x8 v; ull q[2]; u16 u[8]; };

__device__ __forceinline__ s16x8 ld8bf(const void* p, long off, int isf32) {
    FragU f;
    if (isf32) {
        const float* fp = (const float*)p + off;
        f32x4 a = *(const f32x4*)fp;
        f32x4 b = *(const f32x4*)(fp + 4);
        f.u[0]=f2bf(a[0]); f.u[1]=f2bf(a[1]); f.u[2]=f2bf(a[2]); f.u[3]=f2bf(a[3]);
        f.u[4]=f2bf(b[0]); f.u[5]=f2bf(b[1]); f.u[6]=f2bf(b[2]); f.u[7]=f2bf(b[3]);
    } else {
        u32x4 w = *(const u32x4*)((const u16*)p + off);
        f.q[0] = ((ull)w[1] << 32) | w[0];
        f.q[1] = ((ull)w[3] << 32) | w[2];
    }
    return f.v;
}

__device__ __forceinline__ float sigm(float x) { return 1.f / (1.f + __expf(-x)); }

// ---- ws layout (4-byte units). No memset needed: every word is written before read. ----
#define OFF_BKT1  0            // u32[2,000,000]  bucketed edges, hedge side
#define OFF_BKT2  2000000      // u32[2,000,000]  bucketed edges, node side
#define OFF_EX    4000000      // f32[6,400,000]  ex16 [H1][16]
#define OFF_AGG   10400000     // f32[3,200,000]  agg16 [H2][16]
#define OFF_CNT1  13600000     // int[NBK1*NCB]
#define OFF_CNT2  14400768     // int[NBK2*NCB]
#define OFF_TOT   14801152     // int[NGB]
#define OFF_BB1   14802325     // int[NBK1+1]
#define OFF_BB2   14803108     // int[NBK2+1]
#define OFF_BCOMB 14803500     // f32[64]
#define OFF_WIHB  14803564     // u16[12288]
#define OFF_WHHB  14809708     // u16[12288]
#define OFF_WCB   14815852     // u16[1024]
#define OFF_FLAG  14816364     // u32

__global__ void detect_kernel(const u32* __restrict__ xw, u32* __restrict__ flag) {
    __shared__ int cnt;
    if (threadIdx.x == 0) cnt = 0;
    __syncthreads();
    int hits = 0;
    for (int i = threadIdx.x; i < 1024; i += 256) {
        float v = bf2f((u16)(xw[i] & 0xffffu));
        if (!(fabsf(v) < 1e10f)) hits++;
    }
    atomicAdd(&cnt, hits);
    __syncthreads();
    if (threadIdx.x == 0) flag[0] = (cnt >= 16) ? 1u : 0u;
}

__global__ __launch_bounds__(256) void setup_kernel(
        const void* __restrict__ W_conv, const void* __restrict__ b_conv,
        const void* __restrict__ W_mix,  const void* __restrict__ b_mix,
        const void* __restrict__ W_ih,   const void* __restrict__ W_hh,
        float* __restrict__ bcomb, u16* __restrict__ Wihb, u16* __restrict__ Whhb,
        u16* __restrict__ Wcb, const u32* __restrict__ flag) {
    int isf = (int)flag[0];
    int gid = blockIdx.x * 256 + threadIdx.x;
    if (gid < 12288) {
        Wihb[gid] = ldb(W_ih, gid, isf);
    } else if (gid < 24576) {
        int i = gid - 12288;
        Whhb[i] = ldb(W_hh, i, isf);
    } else if (gid < 26624) {
        int i = gid - 24576;
        int j = i >> 5, k = i & 31;
        int t0 = k >> 4, kk = k & 15;
        float acc = 0.f;
        for (int c = 0; c < 64; c++)
            acc += ldv(W_conv, (t0 * 16 + kk) * 64 + c, isf) * ldv(W_mix, (t0 * 64 + c) * 64 + j, isf);
        Wcb[i] = f2bf(acc);
    } else if (gid < 26688) {
        int j = gid - 26624;
        float acc = ldv(b_mix, j, isf);
        for (int c = 0; c < 128; c++)
            acc += ldv(b_conv, c, isf) * ldv(W_mix, c * 64 + j, isf);
        bcomb[j] = acc;
    }
}

// per-block LDS histogram of coarse bucket ids (both sides)
__global__ __launch_bounds__(256) void countK(const int* __restrict__ en, const int* __restrict__ eh,
                                              const int* __restrict__ ea,
                                              int* __restrict__ cnts1, int* __restrict__ cnts2) {
    __shared__ int c1[NBK1], c2[NBK2];
    int blk = blockIdx.x, tid = threadIdx.x;
    for (int i = tid; i < NBK1; i += 256) c1[i] = 0;
    for (int i = tid; i < NBK2; i += 256) c2[i] = 0;
    __syncthreads();
    int s = blk * CHK;
    int e = s + CHK < EE ? s + CHK : EE;
    for (int i = s + tid; i < e; i += 256) {
        int t = ea[i];
        atomicAdd(&c1[(t * MHE + eh[i]) >> 9], 1);
        atomicAdd(&c2[(t * NN + en[i]) >> 9], 1);
    }
    __syncthreads();
    for (int b = tid; b < NBK1; b += 256) cnts1[b * NCB + blk] = c1[b];
    for (int b = tid; b < NBK2; b += 256) cnts2[b * NCB + blk] = c2[b];
}

// per-bucket exclusive scan over its NCB block-counts; emit bucket totals
__global__ __launch_bounds__(256) void scanP1(int* __restrict__ cnts1, int* __restrict__ cnts2,
                                              int* __restrict__ totals) {
    __shared__ int lds[256];
    int g = blockIdx.x, t = threadIdx.x;
    int* base = (g < NBK1) ? (cnts1 + (long)g * NCB) : (cnts2 + (long)(g - NBK1) * NCB);
    int v[4]; int s = 0;
    #pragma unroll
    for (int j = 0; j < 4; j++) { v[j] = base[t * 4 + j]; s += v[j]; }
    lds[t] = s;
    __syncthreads();
    for (int d = 1; d < 256; d <<= 1) {
        int tmp = (t >= d) ? lds[t - d] : 0;
        __syncthreads();
        lds[t] += tmp;
        __syncthreads();
    }
    int run = lds[t] - s;
    #pragma unroll
    for (int j = 0; j < 4; j++) { base[t * 4 + j] = run; run += v[j]; }
    if (t == 255) totals[g] = lds[255];
}

// serial exclusive scan of bucket totals (1173 values)
__global__ void scanP2(const int* __restrict__ totals, int* __restrict__ bb1, int* __restrict__ bb2) {
    if (threadIdx.x != 0 || blockIdx.x != 0) return;
    int run = 0;
    for (int b = 0; b < NBK1; b++) { bb1[b] = run; run += totals[b]; }
    bb1[NBK1] = run;
    run = 0;
    for (int b = 0; b < NBK2; b++) { bb2[b] = run; run += totals[NBK1 + b]; }
    bb2[NBK2] = run;
}

// add bucket base into per-(bucket,block) offsets
__global__ __launch_bounds__(256) void scanP3(int* __restrict__ cnts1, int* __restrict__ cnts2,
                                              const int* __restrict__ bb1, const int* __restrict__ bb2) {
    int g = blockIdx.x, t = threadIdx.x;
    int add; int* base;
    if (g < NBK1) { base = cnts1 + (long)g * NCB; add = bb1[g]; }
    else          { base = cnts2 + (long)(g - NBK1) * NCB; add = bb2[g - NBK1]; }
    #pragma unroll
    for (int j = 0; j < 4; j++) base[t * 4 + j] += add;
}

// place packed payloads into bucket segments; ranks via LDS atomics only
__global__ __launch_bounds__(256) void placeK(const int* __restrict__ en, const int* __restrict__ eh,
                                              const int* __restrict__ ea,
                                              const int* __restrict__ cnts1, const int* __restrict__ cnts2,
                                              u32* __restrict__ bkt1, u32* __restrict__ bkt2) {
    __shared__ int r1[NBK1], r2[NBK2];
    int blk = blockIdx.x, tid = threadIdx.x;
    for (int i = tid; i < NBK1; i += 256) r1[i] = 0;
    for (int i = tid; i < NBK2; i += 256) r2[i] = 0;
    __syncthreads();
    int s = blk * CHK;
    int e = s + CHK < EE ? s + CHK : EE;
    for (int i = s + tid; i < e; i += 256) {
        int t = ea[i]; int n = en[i];
        int k1 = t * MHE + eh[i];
        int k2 = t * NN + n;
        int b1 = k1 >> 9, b2 = k2 >> 9;
        int s1 = cnts1[b1 * NCB + blk] + atomicAdd(&r1[b1], 1);
        int s2 = cnts2[b2 * NCB + blk] + atomicAdd(&r2[b2], 1);
        bkt1[s1] = ((u32)(k1 & 511) << 17) | (u32)n;
        bkt2[s2] = ((u32)(k2 & 511) << 19) | (u32)k1;
    }
}

// hedge-side accumulation: LDS-private 512x16 tile, fold Binv, dense write
__global__ __launch_bounds__(256) void accumA(const u32* __restrict__ bkt1, const int* __restrict__ bb1,
                                              const void* __restrict__ x, float* __restrict__ ex16,
                                              const u32* __restrict__ flag) {
    __shared__ float exl[512 * 16];
    __shared__ float bd[512];
    int isf = (int)flag[0];
    int b = blockIdx.x, tid = threadIdx.x;
    for (int i = tid; i < 512 * 16; i += 256) exl[i] = 0.f;
    for (int i = tid; i < 512; i += 256) bd[i] = 0.f;
    __syncthreads();
    int beg = bb1[b], end = bb1[b + 1];
    int sub = tid & 15, grp = tid >> 4;
    for (int i = beg + grp; i < end; i += 16) {
        u32 p = bkt1[i];
        int l = (int)(p >> 17), n = (int)(p & 0x1FFFFu);
        atomicAdd(&exl[l * 16 + sub], ldv(x, (long)n * 16 + sub, isf));
        if (sub == 0) atomicAdd(&bd[l], 1.0f);
    }
    __syncthreads();
    for (int i = tid; i < 512 * 16; i += 256) {
        int k = i >> 4;
        int key = b * 512 + k;
        if (key < H1) {
            float d = bd[k];
            ex16[(long)key * 16 + (i & 15)] = d > 0.f ? exl[i] * (1.0f / d) : 0.f;
        }
    }
}

// node-side accumulation: gather ex16 by k1, LDS tile, fold Dinv
__global__ __launch_bounds__(256) void accumB(const u32* __restrict__ bkt2, const int* __restrict__ bb2,
                                              const float* __restrict__ ex16, float* __restrict__ agg16) {
    __shared__ float agl[512 * 16];
    __shared__ float dd[512];
    int b = blockIdx.x, tid = threadIdx.x;
    for (int i = tid; i < 512 * 16; i += 256) agl[i] = 0.f;
    for (int i = tid; i < 512; i += 256) dd[i] = 0.f;
    __syncthreads();
    int beg = bb2[b], end = bb2[b + 1];
    int sub = tid & 15, grp = tid >> 4;
    for (int i = beg + grp; i < end; i += 16) {
        u32 p = bkt2[i];
        int l = (int)(p >> 19), k1 = (int)(p & 0x7FFFFu);
        atomicAdd(&agl[l * 16 + sub], ex16[(long)k1 * 16 + sub]);
        if (sub == 0) atomicAdd(&dd[l], 1.0f);
    }
    __syncthreads();
    for (int i = tid; i < 512 * 16; i += 256) {
        int k = i >> 4;
        int key = b * 512 + k;
        if (key < H2) {
            float d = dd[k];
            agg16[(long)key * 16 + (i & 15)] = d > 0.f ? agl[i] * (1.0f / d) : 0.f;
        }
    }
}

// MFMA epilogue; agg16 pre-scaled by Binv and Dinv. (unchanged from passing R7)
__global__ __launch_bounds__(256) void epilogue(const float* __restrict__ agg16,
                                                const float* __restrict__ bcomb,
                                                const u16* __restrict__ Wihb,
                                                const u16* __restrict__ Whhb,
                                                const u16* __restrict__ Wcb,
                                                const void* __restrict__ b_ih, const void* __restrict__ b_hh,
                                                const void* __restrict__ h_prev,
                                                const void* __restrict__ W_out, const void* __restrict__ b_out,
                                                void* __restrict__ out,
                                                const u32* __restrict__ flag) {
    __shared__ u16 hA[4][16][72];
    int isf = (int)flag[0];
    int tid = threadIdx.x;
    int w = tid >> 6, lane = tid & 63;
    int cl = lane & 15, q = lane >> 4;
    u16* hAw = &hA[w][0][0];

    float bcj[4], br[4], bz[4], bin_[4], bhn[4], wo0[4], wo1[4], wo2[4];
    #pragma unroll
    for (int c = 0; c < 4; c++) {
        int j = c * 16 + cl;
        bcj[c]  = bcomb[j];
        br[c]   = ldv(b_ih, j, isf)       + ldv(b_hh, j, isf);
        bz[c]   = ldv(b_ih, 64 + j, isf)  + ldv(b_hh, 64 + j, isf);
        bin_[c] = ldv(b_ih, 128 + j, isf);
        bhn[c]  = ldv(b_hh, 128 + j, isf);
        wo0[c]  = ldv(W_out, (long)j * 64 + 0, isf);
        wo1[c]  = ldv(W_out, (long)j * 64 + 1, isf);
        wo2[c]  = ldv(W_out, (long)j * 64 + 2, isf);
    }
    float bo0 = ldv(b_out, 0, isf), bo1 = ldv(b_out, 1, isf), bo2 = ldv(b_out, 2, isf);

    for (int wt = blockIdx.x * 4 + w; wt < NN / 16; wt += gridDim.x * 4) {
        long nb = (long)wt * 16;
        {
            int m = cl;
            int t0 = q >> 1;
            long nidx = nb + m;
            const float* ap = agg16 + ((long)t0 * NN + nidx) * 16 + (q & 1) * 8;
            f32x4 a0 = *(const f32x4*)ap;
            f32x4 a1 = *(const f32x4*)(ap + 4);
            FragU fa;
            fa.u[0]=f2bf(a0[0]); fa.u[1]=f2bf(a0[1]); fa.u[2]=f2bf(a0[2]); fa.u[3]=f2bf(a0[3]);
            fa.u[4]=f2bf(a1[0]); fa.u[5]=f2bf(a1[1]); fa.u[6]=f2bf(a1[2]); fa.u[7]=f2bf(a1[3]);
            f32x4 hacc[4];
            #pragma unroll
            for (int c = 0; c < 4; c++) {
                hacc[c] = (f32x4){0.f, 0.f, 0.f, 0.f};
                s16x8 bfr = *(const s16x8*)(Wcb + (c * 16 + cl) * 32 + q * 8);
                hacc[c] = __builtin_amdgcn_mfma_f32_16x16x32_bf16(fa.v, bfr, hacc[c], 0, 0, 0);
            }
            #pragma unroll
            for (int c = 0; c < 4; c++) {
                #pragma unroll
                for (int reg = 0; reg < 4; reg++) {
                    int row = q * 4 + reg;
                    float hv = fmaxf(hacc[c][reg] + bcj[c], 0.f);
                    hAw[row * 72 + c * 16 + cl] = f2bf(hv);
                }
            }
        }
        asm volatile("" ::: "memory");
        int m = cl;
        const u16* hrow = hAw + m * 72;
        FragU ha0, ha1;
        #pragma unroll
        for (int j = 0; j < 8; j++) {
            ha0.u[j] = hrow[q * 8 + j];
            ha1.u[j] = hrow[32 + q * 8 + j];
        }
        s16x8 hp0 = ld8bf(h_prev, (nb + m) * 64 + q * 8, isf);
        s16x8 hp1 = ld8bf(h_prev, (nb + m) * 64 + 32 + q * 8, isf);

        f32x4 accr[4], accz[4], accin[4], acchn[4];
        #pragma unroll
        for (int c = 0; c < 4; c++) {
            accr[c]  = (f32x4){br[c], br[c], br[c], br[c]};
            accz[c]  = (f32x4){bz[c], bz[c], bz[c], bz[c]};
            accin[c] = (f32x4){bin_[c], bin_[c], bin_[c], bin_[c]};
            acchn[c] = (f32x4){bhn[c], bhn[c], bhn[c], bhn[c]};
        }
        #pragma unroll
        for (int s = 0; s < 2; s++) {
            s16x8 hf  = s ? ha1.v : ha0.v;
            s16x8 hpf = s ? hp1 : hp0;
            int ko = s * 32 + q * 8;
            #pragma unroll
            for (int c = 0; c < 4; c++) {
                int rr = c * 16 + cl;
                s16x8 bir  = *(const s16x8*)(Wihb + (long)rr * 64 + ko);
                s16x8 bhr  = *(const s16x8*)(Whhb + (long)rr * 64 + ko);
                s16x8 biz  = *(const s16x8*)(Wihb + (long)(64 + rr) * 64 + ko);
                s16x8 bhz  = *(const s16x8*)(Whhb + (long)(64 + rr) * 64 + ko);
                s16x8 bin2 = *(const s16x8*)(Wihb + (long)(128 + rr) * 64 + ko);
                s16x8 bhn2 = *(const s16x8*)(Whhb + (long)(128 + rr) * 64 + ko);
                accr[c]  = __builtin_amdgcn_mfma_f32_16x16x32_bf16(hf,  bir, accr[c], 0, 0, 0);
                accr[c]  = __builtin_amdgcn_mfma_f32_16x16x32_bf16(hpf, bhr, accr[c], 0, 0, 0);
                accz[c]  = __builtin_amdgcn_mfma_f32_16x16x32_bf16(hf,  biz, accz[c], 0, 0, 0);
                accz[c]  = __builtin_amdgcn_mfma_f32_16x16x32_bf16(hpf, bhz, accz[c], 0, 0, 0);
                accin[c] = __builtin_amdgcn_mfma_f32_16x16x32_bf16(hf,  bin2, accin[c], 0, 0, 0);
                acchn[c] = __builtin_amdgcn_mfma_f32_16x16x32_bf16(hpf, bhn2, acchn[c], 0, 0, 0);
            }
        }
        float p0[4] = {0,0,0,0}, p1[4] = {0,0,0,0}, p2[4] = {0,0,0,0};
        #pragma unroll
        for (int c = 0; c < 4; c++) {
            #pragma unroll
            for (int reg = 0; reg < 4; reg++) {
                float rr = sigm(accr[c][reg]);
                float zz = sigm(accz[c][reg]);
                float ng = tanhf(accin[c][reg] + rr * acchn[c][reg]);
                long n = nb + q * 4 + reg;
                long j = c * 16 + cl;
                float hp = ldv(h_prev, n * 64 + j, isf);
                float hx = (1.f - zz) * ng + zz * hp;
                stv(out, n * 64 + j, hx, isf);
                p0[reg] += hx * wo0[c];
                p1[reg] += hx * wo1[c];
                p2[reg] += hx * wo2[c];
            }
        }
        #pragma unroll
        for (int reg = 0; reg < 4; reg++) {
            #pragma unroll
            for (int off2 = 1; off2 < 16; off2 <<= 1) {
                p0[reg] += __shfl_xor(p0[reg], off2);
                p1[reg] += __shfl_xor(p1[reg], off2);
                p2[reg] += __shfl_xor(p2[reg], off2);
            }
        }
        if (cl == 0) {
            #pragma unroll
            for (int reg = 0; reg < 4; reg++) {
                long n = nb + q * 4 + reg;
                long pb = (long)NN * 64 + n * 3;
                stv(out, pb + 0, p0[reg] + bo0, isf);
                stv(out, pb + 1, p1[reg] + bo1, isf);
                stv(out, pb + 2, p2[reg] + bo2, isf);
            }
        }
    }
}

extern "C" void kernel_launch(void* const* d_in, const int* in_sizes, int n_in,
                              void* d_out, int out_size, void* d_ws, size_t ws_size,
                              hipStream_t stream) {
    const void* x      = d_in[0];
    const void* h_prev = d_in[1];
    const int* en      = (const int*)d_in[2];
    const int* eh      = (const int*)d_in[3];
    const int* ea      = (const int*)d_in[4];
    const void* W_conv = d_in[5];
    const void* b_conv = d_in[6];
    const void* W_mix  = d_in[7];
    const void* b_mix  = d_in[8];
    const void* W_ih   = d_in[9];
    const void* W_hh   = d_in[10];
    const void* b_ih   = d_in[11];
    const void* b_hh   = d_in[12];
    const void* W_out  = d_in[13];
    const void* b_out  = d_in[14];
    void* out          = d_out;

    float* ws    = (float*)d_ws;
    u32* bkt1    = (u32*)(ws + OFF_BKT1);
    u32* bkt2    = (u32*)(ws + OFF_BKT2);
    float* ex16  = ws + OFF_EX;
    float* agg16 = ws + OFF_AGG;
    int* cnts1   = (int*)(ws + OFF_CNT1);
    int* cnts2   = (int*)(ws + OFF_CNT2);
    int* totals  = (int*)(ws + OFF_TOT);
    int* bb1     = (int*)(ws + OFF_BB1);
    int* bb2     = (int*)(ws + OFF_BB2);
    float* bcomb = ws + OFF_BCOMB;
    u16* Wihb    = (u16*)(ws + OFF_WIHB);
    u16* Whhb    = (u16*)(ws + OFF_WHHB);
    u16* Wcb     = (u16*)(ws + OFF_WCB);
    u32* flag    = (u32*)(ws + OFF_FLAG);

    detect_kernel<<<1, 256, 0, stream>>>((const u32*)x, flag);
    setup_kernel<<<105, 256, 0, stream>>>(W_conv, b_conv, W_mix, b_mix, W_ih, W_hh,
                                          bcomb, Wihb, Whhb, Wcb, flag);
    countK<<<NCB, 256, 0, stream>>>(en, eh, ea, cnts1, cnts2);
    scanP1<<<NGB, 256, 0, stream>>>(cnts1, cnts2, totals);
    scanP2<<<1, 64, 0, stream>>>(totals, bb1, bb2);
    scanP3<<<NGB, 256, 0, stream>>>(cnts1, cnts2, bb1, bb2);
    placeK<<<NCB, 256, 0, stream>>>(en, eh, ea, cnts1, cnts2, bkt1, bkt2);
    accumA<<<NBK1, 256, 0, stream>>>(bkt1, bb1, x, ex16, flag);
    accumB<<<NBK2, 256, 0, stream>>>(bkt2, bb2, ex16, agg16);
    epilogue<<<1563, 256, 0, stream>>>(agg16, bcomb, Wihb, Whhb, Wcb,
                                       b_ih, b_hh, h_prev, W_out, b_out, out, flag);
}

// Round 9
// 790.099 us; speedup vs baseline: 1.0481x; 1.0481x over previous
//
#include <hip/hip_runtime.h>

#define NN      100000
#define MHE     200000
#define EE      2000000
#define H1      400000      // hedge keys (2 types)
#define H2      200000      // node keys (2 types)
#define NBK1    782         // ceil(H1/512)
#define NBK2    391         // ceil(H2/512)
#define NGB     1173        // NBK1+NBK2
#define NCB     1024        // counting blocks
#define CHK     1954        // edges per counting block

typedef unsigned short u16;
typedef unsigned int   u32;
typedef unsigned long long ull;
typedef __attribute__((ext_vector_type(8))) short  s16x8;
typedef __attribute__((ext_vector_type(4))) float  f32x4;
typedef __attribute__((ext_vector_type(4))) unsigned int u32x4;

__device__ __forceinline__ float bf2f(u16 u) { return __uint_as_float(((u32)u) << 16); }
__device__ __forceinline__ u16 f2bf(float f) {
    u32 u = __float_as_uint(f);
    return (u16)((u + 0x7fffu + ((u >> 16) & 1u)) >> 16);
}
__device__ __forceinline__ float ldv(const void* p, long i, int isf32) {
    return isf32 ? ((const float*)p)[i] : bf2f(((const u16*)p)[i]);
}
__device__ __forceinline__ u16 ldb(const void* p, long i, int isf32) {
    return isf32 ? f2bf(((const float*)p)[i]) : ((const u16*)p)[i];
}
__device__ __forceinline__ void stv(void* p, long i, float v, int isf32) {
    if (isf32) ((float*)p)[i] = v;
    else       ((u16*)p)[i] = f2bf(v);
}

union FragU { s16x8 v; ull q[2]; u16 u[8]; };

__device__ __forceinline__ s16x8 ld8bf(const void* p, long off, int isf32) {
    FragU f;
    if (isf32) {
        const float* fp = (const float*)p + off;
        f32x4 a = *(const f32x4*)fp;
        f32x4 b = *(const f32x4*)(fp + 4);
        f.u[0]=f2bf(a[0]); f.u[1]=f2bf(a[1]); f.u[2]=f2bf(a[2]); f.u[3]=f2bf(a[3]);
        f.u[4]=f2bf(b[0]); f.u[5]=f2bf(b[1]); f.u[6]=f2bf(b[2]); f.u[7]=f2bf(b[3]);
    } else {
        u32x4 w = *(const u32x4*)((const u16*)p + off);
        f.q[0] = ((ull)w[1] << 32) | w[0];
        f.q[1] = ((ull)w[3] << 32) | w[2];
    }
    return f.v;
}

__device__ __forceinline__ float sigm(float x) { return 1.f / (1.f + __expf(-x)); }

// ---- ws layout (4-byte units). No memset needed. ----
#define OFF_BKT1  0            // u32[2,000,000]
#define OFF_BKT2  2000000      // u32[2,000,000]
#define OFF_EX    4000000      // f32[6,400,000]  ex16 [H1][16]
#define OFF_AGG   10400000     // f32[3,200,000]  agg16 [H2][16]
#define OFF_CNT1  13600000     // int[NBK1*NCB]
#define OFF_CNT2  14400768     // int[NBK2*NCB]
#define OFF_TOT   14801152     // int[NGB]
#define OFF_BB1   14802325     // int[NBK1+1]
#define OFF_BB2   14803108     // int[NBK2+1]
#define OFF_BCOMB 14803500     // f32[64]
#define OFF_WIHB  14803564     // u16[12288]
#define OFF_WHHB  14809708     // u16[12288]
#define OFF_WCB   14815852     // u16[1024]
#define OFF_FLAG  14816364     // u32

__global__ void detect_kernel(const u32* __restrict__ xw, u32* __restrict__ flag) {
    __shared__ int cnt;
    if (threadIdx.x == 0) cnt = 0;
    __syncthreads();
    int hits = 0;
    for (int i = threadIdx.x; i < 1024; i += 256) {
        float v = bf2f((u16)(xw[i] & 0xffffu));
        if (!(fabsf(v) < 1e10f)) hits++;
    }
    atomicAdd(&cnt, hits);
    __syncthreads();
    if (threadIdx.x == 0) flag[0] = (cnt >= 16) ? 1u : 0u;
}

__global__ __launch_bounds__(256) void setup_kernel(
        const void* __restrict__ W_conv, const void* __restrict__ b_conv,
        const void* __restrict__ W_mix,  const void* __restrict__ b_mix,
        const void* __restrict__ W_ih,   const void* __restrict__ W_hh,
        float* __restrict__ bcomb, u16* __restrict__ Wihb, u16* __restrict__ Whhb,
        u16* __restrict__ Wcb, const u32* __restrict__ flag) {
    int isf = (int)flag[0];
    int gid = blockIdx.x * 256 + threadIdx.x;
    if (gid < 12288) {
        Wihb[gid] = ldb(W_ih, gid, isf);
    } else if (gid < 24576) {
        int i = gid - 12288;
        Whhb[i] = ldb(W_hh, i, isf);
    } else if (gid < 26624) {
        int i = gid - 24576;
        int j = i >> 5, k = i & 31;
        int t0 = k >> 4, kk = k & 15;
        float acc = 0.f;
        for (int c = 0; c < 64; c++)
            acc += ldv(W_conv, (t0 * 16 + kk) * 64 + c, isf) * ldv(W_mix, (t0 * 64 + c) * 64 + j, isf);
        Wcb[i] = f2bf(acc);
    } else if (gid < 26688) {
        int j = gid - 26624;
        float acc = ldv(b_mix, j, isf);
        for (int c = 0; c < 128; c++)
            acc += ldv(b_conv, c, isf) * ldv(W_mix, c * 64 + j, isf);
        bcomb[j] = acc;
    }
}

// per-block LDS histogram of coarse bucket ids (both sides). 512 threads.
__global__ __launch_bounds__(512) void countK(const int* __restrict__ en, const int* __restrict__ eh,
                                              const int* __restrict__ ea,
                                              int* __restrict__ cnts1, int* __restrict__ cnts2) {
    __shared__ int c1[NBK1], c2[NBK2];
    int blk = blockIdx.x, tid = threadIdx.x;
    for (int i = tid; i < NBK1; i += 512) c1[i] = 0;
    for (int i = tid; i < NBK2; i += 512) c2[i] = 0;
    __syncthreads();
    int s = blk * CHK;
    int e = s + CHK < EE ? s + CHK : EE;
    for (int i = s + tid; i < e; i += 512) {
        int t = ea[i];
        atomicAdd(&c1[(t * MHE + eh[i]) >> 9], 1);
        atomicAdd(&c2[(t * NN + en[i]) >> 9], 1);
    }
    __syncthreads();
    for (int b = tid; b < NBK1; b += 512) cnts1[b * NCB + blk] = c1[b];
    for (int b = tid; b < NBK2; b += 512) cnts2[b * NCB + blk] = c2[b];
}

__global__ __launch_bounds__(256) void scanP1(int* __restrict__ cnts1, int* __restrict__ cnts2,
                                              int* __restrict__ totals) {
    __shared__ int lds[256];
    int g = blockIdx.x, t = threadIdx.x;
    int* base = (g < NBK1) ? (cnts1 + (long)g * NCB) : (cnts2 + (long)(g - NBK1) * NCB);
    int v[4]; int s = 0;
    #pragma unroll
    for (int j = 0; j < 4; j++) { v[j] = base[t * 4 + j]; s += v[j]; }
    lds[t] = s;
    __syncthreads();
    for (int d = 1; d < 256; d <<= 1) {
        int tmp = (t >= d) ? lds[t - d] : 0;
        __syncthreads();
        lds[t] += tmp;
        __syncthreads();
    }
    int run = lds[t] - s;
    #pragma unroll
    for (int j = 0; j < 4; j++) { base[t * 4 + j] = run; run += v[j]; }
    if (t == 255) totals[g] = lds[255];
}

__global__ void scanP2(const int* __restrict__ totals, int* __restrict__ bb1, int* __restrict__ bb2) {
    if (threadIdx.x != 0 || blockIdx.x != 0) return;
    int run = 0;
    for (int b = 0; b < NBK1; b++) { bb1[b] = run; run += totals[b]; }
    bb1[NBK1] = run;
    run = 0;
    for (int b = 0; b < NBK2; b++) { bb2[b] = run; run += totals[NBK1 + b]; }
    bb2[NBK2] = run;
}

__global__ __launch_bounds__(256) void scanP3(int* __restrict__ cnts1, int* __restrict__ cnts2,
                                              const int* __restrict__ bb1, const int* __restrict__ bb2) {
    int g = blockIdx.x, t = threadIdx.x;
    int add; int* base;
    if (g < NBK1) { base = cnts1 + (long)g * NCB; add = bb1[g]; }
    else          { base = cnts2 + (long)(g - NBK1) * NCB; add = bb2[g - NBK1]; }
    #pragma unroll
    for (int j = 0; j < 4; j++) base[t * 4 + j] += add;
}

// place packed payloads into bucket segments; ranks via LDS atomics. 1024 threads.
__global__ __launch_bounds__(1024) void placeK(const int* __restrict__ en, const int* __restrict__ eh,
                                               const int* __restrict__ ea,
                                               const int* __restrict__ cnts1, const int* __restrict__ cnts2,
                                               u32* __restrict__ bkt1, u32* __restrict__ bkt2) {
    __shared__ int r1[NBK1], r2[NBK2];
    int blk = blockIdx.x, tid = threadIdx.x;
    for (int i = tid; i < NBK1; i += 1024) r1[i] = 0;
    for (int i = tid; i < NBK2; i += 1024) r2[i] = 0;
    __syncthreads();
    int s = blk * CHK;
    int e = s + CHK < EE ? s + CHK : EE;
    for (int i = s + tid; i < e; i += 1024) {
        int t = ea[i]; int n = en[i];
        int k1 = t * MHE + eh[i];
        int k2 = t * NN + n;
        int b1 = k1 >> 9, b2 = k2 >> 9;
        int s1 = cnts1[b1 * NCB + blk] + atomicAdd(&r1[b1], 1);
        int s2 = cnts2[b2 * NCB + blk] + atomicAdd(&r2[b2], 1);
        bkt1[s1] = ((u32)(k1 & 511) << 17) | (u32)n;
        bkt2[s2] = ((u32)(k2 & 511) << 19) | (u32)k1;
    }
}

// hedge-side accumulation: 1024 threads (64 groups), batch-4 pipelined gathers.
__global__ __launch_bounds__(1024) void accumA(const u32* __restrict__ bkt1, const int* __restrict__ bb1,
                                               const void* __restrict__ x, float* __restrict__ ex16,
                                               const u32* __restrict__ flag) {
    __shared__ float exl[512 * 16];
    __shared__ float bd[512];
    int isf = (int)flag[0];
    int b = blockIdx.x, tid = threadIdx.x;
    for (int i = tid; i < 512 * 16; i += 1024) exl[i] = 0.f;
    if (tid < 512) bd[tid] = 0.f;
    __syncthreads();
    int beg = bb1[b], end = bb1[b + 1];
    int sub = tid & 15, grp = tid >> 4;           // 64 groups
    int i = beg + grp;
    for (; i + 192 < end; i += 256) {
        u32 p0 = bkt1[i], p1 = bkt1[i + 64], p2 = bkt1[i + 128], p3 = bkt1[i + 192];
        float v0 = ldv(x, (long)(p0 & 0x1FFFFu) * 16 + sub, isf);
        float v1 = ldv(x, (long)(p1 & 0x1FFFFu) * 16 + sub, isf);
        float v2 = ldv(x, (long)(p2 & 0x1FFFFu) * 16 + sub, isf);
        float v3 = ldv(x, (long)(p3 & 0x1FFFFu) * 16 + sub, isf);
        atomicAdd(&exl[(p0 >> 17) * 16 + sub], v0);
        atomicAdd(&exl[(p1 >> 17) * 16 + sub], v1);
        atomicAdd(&exl[(p2 >> 17) * 16 + sub], v2);
        atomicAdd(&exl[(p3 >> 17) * 16 + sub], v3);
        if (sub == 0) {
            atomicAdd(&bd[p0 >> 17], 1.0f);
            atomicAdd(&bd[p1 >> 17], 1.0f);
            atomicAdd(&bd[p2 >> 17], 1.0f);
            atomicAdd(&bd[p3 >> 17], 1.0f);
        }
    }
    for (; i < end; i += 64) {
        u32 p = bkt1[i];
        float v = ldv(x, (long)(p & 0x1FFFFu) * 16 + sub, isf);
        atomicAdd(&exl[(p >> 17) * 16 + sub], v);
        if (sub == 0) atomicAdd(&bd[p >> 17], 1.0f);
    }
    __syncthreads();
    for (int j = tid; j < 512 * 16; j += 1024) {
        int k = j >> 4;
        int key = b * 512 + k;
        if (key < H1) {
            float d = bd[k];
            ex16[(long)key * 16 + (j & 15)] = d > 0.f ? exl[j] * (1.0f / d) : 0.f;
        }
    }
}

// node-side accumulation: 1024 threads, batch-4 pipelined ex16 gathers.
__global__ __launch_bounds__(1024) void accumB(const u32* __restrict__ bkt2, const int* __restrict__ bb2,
                                               const float* __restrict__ ex16, float* __restrict__ agg16) {
    __shared__ float agl[512 * 16];
    __shared__ float dd[512];
    int b = blockIdx.x, tid = threadIdx.x;
    for (int i = tid; i < 512 * 16; i += 1024) agl[i] = 0.f;
    if (tid < 512) dd[tid] = 0.f;
    __syncthreads();
    int beg = bb2[b], end = bb2[b + 1];
    int sub = tid & 15, grp = tid >> 4;
    int i = beg + grp;
    for (; i + 192 < end; i += 256) {
        u32 p0 = bkt2[i], p1 = bkt2[i + 64], p2 = bkt2[i + 128], p3 = bkt2[i + 192];
        float v0 = ex16[(long)(p0 & 0x7FFFFu) * 16 + sub];
        float v1 = ex16[(long)(p1 & 0x7FFFFu) * 16 + sub];
        float v2 = ex16[(long)(p2 & 0x7FFFFu) * 16 + sub];
        float v3 = ex16[(long)(p3 & 0x7FFFFu) * 16 + sub];
        atomicAdd(&agl[(p0 >> 19) * 16 + sub], v0);
        atomicAdd(&agl[(p1 >> 19) * 16 + sub], v1);
        atomicAdd(&agl[(p2 >> 19) * 16 + sub], v2);
        atomicAdd(&agl[(p3 >> 19) * 16 + sub], v3);
        if (sub == 0) {
            atomicAdd(&dd[p0 >> 19], 1.0f);
            atomicAdd(&dd[p1 >> 19], 1.0f);
            atomicAdd(&dd[p2 >> 19], 1.0f);
            atomicAdd(&dd[p3 >> 19], 1.0f);
        }
    }
    for (; i < end; i += 64) {
        u32 p = bkt2[i];
        float v = ex16[(long)(p & 0x7FFFFu) * 16 + sub];
        atomicAdd(&agl[(p >> 19) * 16 + sub], v);
        if (sub == 0) atomicAdd(&dd[p >> 19], 1.0f);
    }
    __syncthreads();
    for (int j = tid; j < 512 * 16; j += 1024) {
        int k = j >> 4;
        int key = b * 512 + k;
        if (key < H2) {
            float d = dd[k];
            agg16[(long)key * 16 + (j & 15)] = d > 0.f ? agl[j] * (1.0f / d) : 0.f;
        }
    }
}

// MFMA epilogue; agg16 pre-scaled by Binv and Dinv. (unchanged, passing since R7)
__global__ __launch_bounds__(256) void epilogue(const float* __restrict__ agg16,
                                                const float* __restrict__ bcomb,
                                                const u16* __restrict__ Wihb,
                                                const u16* __restrict__ Whhb,
                                                const u16* __restrict__ Wcb,
                                                const void* __restrict__ b_ih, const void* __restrict__ b_hh,
                                                const void* __restrict__ h_prev,
                                                const void* __restrict__ W_out, const void* __restrict__ b_out,
                                                void* __restrict__ out,
                                                const u32* __restrict__ flag) {
    __shared__ u16 hA[4][16][72];
    int isf = (int)flag[0];
    int tid = threadIdx.x;
    int w = tid >> 6, lane = tid & 63;
    int cl = lane & 15, q = lane >> 4;
    u16* hAw = &hA[w][0][0];

    float bcj[4], br[4], bz[4], bin_[4], bhn[4], wo0[4], wo1[4], wo2[4];
    #pragma unroll
    for (int c = 0; c < 4; c++) {
        int j = c * 16 + cl;
        bcj[c]  = bcomb[j];
        br[c]   = ldv(b_ih, j, isf)       + ldv(b_hh, j, isf);
        bz[c]   = ldv(b_ih, 64 + j, isf)  + ldv(b_hh, 64 + j, isf);
        bin_[c] = ldv(b_ih, 128 + j, isf);
        bhn[c]  = ldv(b_hh, 128 + j, isf);
        wo0[c]  = ldv(W_out, (long)j * 64 + 0, isf);
        wo1[c]  = ldv(W_out, (long)j * 64 + 1, isf);
        wo2[c]  = ldv(W_out, (long)j * 64 + 2, isf);
    }
    float bo0 = ldv(b_out, 0, isf), bo1 = ldv(b_out, 1, isf), bo2 = ldv(b_out, 2, isf);

    for (int wt = blockIdx.x * 4 + w; wt < NN / 16; wt += gridDim.x * 4) {
        long nb = (long)wt * 16;
        {
            int m = cl;
            int t0 = q >> 1;
            long nidx = nb + m;
            const float* ap = agg16 + ((long)t0 * NN + nidx) * 16 + (q & 1) * 8;
            f32x4 a0 = *(const f32x4*)ap;
            f32x4 a1 = *(const f32x4*)(ap + 4);
            FragU fa;
            fa.u[0]=f2bf(a0[0]); fa.u[1]=f2bf(a0[1]); fa.u[2]=f2bf(a0[2]); fa.u[3]=f2bf(a0[3]);
            fa.u[4]=f2bf(a1[0]); fa.u[5]=f2bf(a1[1]); fa.u[6]=f2bf(a1[2]); fa.u[7]=f2bf(a1[3]);
            f32x4 hacc[4];
            #pragma unroll
            for (int c = 0; c < 4; c++) {
                hacc[c] = (f32x4){0.f, 0.f, 0.f, 0.f};
                s16x8 bfr = *(const s16x8*)(Wcb + (c * 16 + cl) * 32 + q * 8);
                hacc[c] = __builtin_amdgcn_mfma_f32_16x16x32_bf16(fa.v, bfr, hacc[c], 0, 0, 0);
            }
            #pragma unroll
            for (int c = 0; c < 4; c++) {
                #pragma unroll
                for (int reg = 0; reg < 4; reg++) {
                    int row = q * 4 + reg;
                    float hv = fmaxf(hacc[c][reg] + bcj[c], 0.f);
                    hAw[row * 72 + c * 16 + cl] = f2bf(hv);
                }
            }
        }
        asm volatile("" ::: "memory");
        int m = cl;
        const u16* hrow = hAw + m * 72;
        FragU ha0, ha1;
        #pragma unroll
        for (int j = 0; j < 8; j++) {
            ha0.u[j] = hrow[q * 8 + j];
            ha1.u[j] = hrow[32 + q * 8 + j];
        }
        s16x8 hp0 = ld8bf(h_prev, (nb + m) * 64 + q * 8, isf);
        s16x8 hp1 = ld8bf(h_prev, (nb + m) * 64 + 32 + q * 8, isf);

        f32x4 accr[4], accz[4], accin[4], acchn[4];
        #pragma unroll
        for (int c = 0; c < 4; c++) {
            accr[c]  = (f32x4){br[c], br[c], br[c], br[c]};
            accz[c]  = (f32x4){bz[c], bz[c], bz[c], bz[c]};
            accin[c] = (f32x4){bin_[c], bin_[c], bin_[c], bin_[c]};
            acchn[c] = (f32x4){bhn[c], bhn[c], bhn[c], bhn[c]};
        }
        #pragma unroll
        for (int s = 0; s < 2; s++) {
            s16x8 hf  = s ? ha1.v : ha0.v;
            s16x8 hpf = s ? hp1 : hp0;
            int ko = s * 32 + q * 8;
            #pragma unroll
            for (int c = 0; c < 4; c++) {
                int rr = c * 16 + cl;
                s16x8 bir  = *(const s16x8*)(Wihb + (long)rr * 64 + ko);
                s16x8 bhr  = *(const s16x8*)(Whhb + (long)rr * 64 + ko);
                s16x8 biz  = *(const s16x8*)(Wihb + (long)(64 + rr) * 64 + ko);
                s16x8 bhz  = *(const s16x8*)(Whhb + (long)(64 + rr) * 64 + ko);
                s16x8 bin2 = *(const s16x8*)(Wihb + (long)(128 + rr) * 64 + ko);
                s16x8 bhn2 = *(const s16x8*)(Whhb + (long)(128 + rr) * 64 + ko);
                accr[c]  = __builtin_amdgcn_mfma_f32_16x16x32_bf16(hf,  bir, accr[c], 0, 0, 0);
                accr[c]  = __builtin_amdgcn_mfma_f32_16x16x32_bf16(hpf, bhr, accr[c], 0, 0, 0);
                accz[c]  = __builtin_amdgcn_mfma_f32_16x16x32_bf16(hf,  biz, accz[c], 0, 0, 0);
                accz[c]  = __builtin_amdgcn_mfma_f32_16x16x32_bf16(hpf, bhz, accz[c], 0, 0, 0);
                accin[c] = __builtin_amdgcn_mfma_f32_16x16x32_bf16(hf,  bin2, accin[c], 0, 0, 0);
                acchn[c] = __builtin_amdgcn_mfma_f32_16x16x32_bf16(hpf, bhn2, acchn[c], 0, 0, 0);
            }
        }
        float p0[4] = {0,0,0,0}, p1[4] = {0,0,0,0}, p2[4] = {0,0,0,0};
        #pragma unroll
        for (int c = 0; c < 4; c++) {
            #pragma unroll
            for (int reg = 0; reg < 4; reg++) {
                float rr = sigm(accr[c][reg]);
                float zz = sigm(accz[c][reg]);
                float ng = tanhf(accin[c][reg] + rr * acchn[c][reg]);
                long n = nb + q * 4 + reg;
                long j = c * 16 + cl;
                float hp = ldv(h_prev, n * 64 + j, isf);
                float hx = (1.f - zz) * ng + zz * hp;
                stv(out, n * 64 + j, hx, isf);
                p0[reg] += hx * wo0[c];
                p1[reg] += hx * wo1[c];
                p2[reg] += hx * wo2[c];
            }
        }
        #pragma unroll
        for (int reg = 0; reg < 4; reg++) {
            #pragma unroll
            for (int off2 = 1; off2 < 16; off2 <<= 1) {
                p0[reg] += __shfl_xor(p0[reg], off2);
                p1[reg] += __shfl_xor(p1[reg], off2);
                p2[reg] += __shfl_xor(p2[reg], off2);
            }
        }
        if (cl == 0) {
            #pragma unroll
            for (int reg = 0; reg < 4; reg++) {
                long n = nb + q * 4 + reg;
                long pb = (long)NN * 64 + n * 3;
                stv(out, pb + 0, p0[reg] + bo0, isf);
                stv(out, pb + 1, p1[reg] + bo1, isf);
                stv(out, pb + 2, p2[reg] + bo2, isf);
            }
        }
    }
}

extern "C" void kernel_launch(void* const* d_in, const int* in_sizes, int n_in,
                              void* d_out, int out_size, void* d_ws, size_t ws_size,
                              hipStream_t stream) {
    const void* x      = d_in[0];
    const void* h_prev = d_in[1];
    const int* en      = (const int*)d_in[2];
    const int* eh      = (const int*)d_in[3];
    const int* ea      = (const int*)d_in[4];
    const void* W_conv = d_in[5];
    const void* b_conv = d_in[6];
    const void* W_mix  = d_in[7];
    const void* b_mix  = d_in[8];
    const void* W_ih   = d_in[9];
    const void* W_hh   = d_in[10];
    const void* b_ih   = d_in[11];
    const void* b_hh   = d_in[12];
    const void* W_out  = d_in[13];
    const void* b_out  = d_in[14];
    void* out          = d_out;

    float* ws    = (float*)d_ws;
    u32* bkt1    = (u32*)(ws + OFF_BKT1);
    u32* bkt2    = (u32*)(ws + OFF_BKT2);
    float* ex16  = ws + OFF_EX;
    float* agg16 = ws + OFF_AGG;
    int* cnts1   = (int*)(ws + OFF_CNT1);
    int* cnts2   = (int*)(ws + OFF_CNT2);
    int* totals  = (int*)(ws + OFF_TOT);
    int* bb1     = (int*)(ws + OFF_BB1);
    int* bb2     = (int*)(ws + OFF_BB2);
    float* bcomb = ws + OFF_BCOMB;
    u16* Wihb    = (u16*)(ws + OFF_WIHB);
    u16* Whhb    = (u16*)(ws + OFF_WHHB);
    u16* Wcb     = (u16*)(ws + OFF_WCB);
    u32* flag    = (u32*)(ws + OFF_FLAG);

    detect_kernel<<<1, 256, 0, stream>>>((const u32*)x, flag);
    setup_kernel<<<105, 256, 0, stream>>>(W_conv, b_conv, W_mix, b_mix, W_ih, W_hh,
                                          bcomb, Wihb, Whhb, Wcb, flag);
    countK<<<NCB, 512, 0, stream>>>(en, eh, ea, cnts1, cnts2);
    scanP1<<<NGB, 256, 0, stream>>>(cnts1, cnts2, totals);
    scanP2<<<1, 64, 0, stream>>>(totals, bb1, bb2);
    scanP3<<<NGB, 256, 0, stream>>>(cnts1, cnts2, bb1, bb2);
    placeK<<<NCB, 1024, 0, stream>>>(en, eh, ea, cnts1, cnts2, bkt1, bkt2);
    accumA<<<NBK1, 1024, 0, stream>>>(bkt1, bb1, x, ex16, flag);
    accumB<<<NBK2, 1024, 0, stream>>>(bkt2, bb2, ex16, agg16);
    epilogue<<<1563, 256, 0, stream>>>(agg16, bcomb, Wihb, Whhb, Wcb,
                                       b_ih, b_hh, h_prev, W_out, b_out, out, flag);
}

// Round 10
// 772.252 us; speedup vs baseline: 1.0723x; 1.0231x over previous
//
#include <hip/hip_runtime.h>

#define NN      100000
#define MHE     200000
#define EE      2000000
#define H1      400000      // hedge keys (2 types)
#define H2      200000      // node keys (2 types)
#define NBK1    1563        // ceil(H1/256)
#define NBK2    782         // ceil(H2/256)
#define NGB     2345        // NBK1+NBK2
#define NCB     1024        // counting blocks
#define CHK     1954        // edges per counting block

typedef unsigned short u16;
typedef unsigned int   u32;
typedef unsigned long long ull;
typedef __attribute__((ext_vector_type(8))) short  s16x8;
typedef __attribute__((ext_vector_type(4))) float  f32x4;
typedef __attribute__((ext_vector_type(4))) unsigned int u32x4;

__device__ __forceinline__ float bf2f(u16 u) { return __uint_as_float(((u32)u) << 16); }
__device__ __forceinline__ u16 f2bf(float f) {
    u32 u = __float_as_uint(f);
    return (u16)((u + 0x7fffu + ((u >> 16) & 1u)) >> 16);
}
__device__ __forceinline__ float ldv(const void* p, long i, int isf32) {
    return isf32 ? ((const float*)p)[i] : bf2f(((const u16*)p)[i]);
}
__device__ __forceinline__ u16 ldb(const void* p, long i, int isf32) {
    return isf32 ? f2bf(((const float*)p)[i]) : ((const u16*)p)[i];
}
__device__ __forceinline__ void stv(void* p, long i, float v, int isf32) {
    if (isf32) ((float*)p)[i] = v;
    else       ((u16*)p)[i] = f2bf(v);
}

union FragU { s16x8 v; ull q[2]; u16 u[8]; };

__device__ __forceinline__ s16x8 ld8bf(const void* p, long off, int isf32) {
    FragU f;
    if (isf32) {
        const float* fp = (const float*)p + off;
        f32x4 a = *(const f32x4*)fp;
        f32x4 b = *(const f32x4*)(fp + 4);
        f.u[0]=f2bf(a[0]); f.u[1]=f2bf(a[1]); f.u[2]=f2bf(a[2]); f.u[3]=f2bf(a[3]);
        f.u[4]=f2bf(b[0]); f.u[5]=f2bf(b[1]); f.u[6]=f2bf(b[2]); f.u[7]=f2bf(b[3]);
    } else {
        u32x4 w = *(const u32x4*)((const u16*)p + off);
        f.q[0] = ((ull)w[1] << 32) | w[0];
        f.q[1] = ((ull)w[3] << 32) | w[2];
    }
    return f.v;
}

__device__ __forceinline__ float sigm(float x) { return 1.f / (1.f + __expf(-x)); }

// ---- ws layout (4-byte units). No memset needed. ----
#define OFF_BKT1  0            // u32[2,000,000]
#define OFF_BKT2  2000000      // u32[2,000,000]
#define OFF_EXB   4000000      // u32[3,200,000]  exb [H1][8] bf16-pairs
#define OFF_AGG   7200000      // f32[3,200,000]  agg16 [H2][16]
#define OFF_XB    10400000     // u32[800,000]    xb [NN][8] bf16-pairs
#define OFF_CNT1  11200000     // int[NBK1*NCB]
#define OFF_CNT2  12800512     // int[NBK2*NCB]
#define OFF_TOT   13601280     // int[NGB]
#define OFF_BB1   13603625     // int[NBK1+1]
#define OFF_BB2   13605189     // int[NBK2+1]
#define OFF_BCOMB 13605972     // f32[64]
#define OFF_WIHB  13606036     // u16[12288]
#define OFF_WHHB  13612180     // u16[12288]
#define OFF_WCB   13618324     // u16[1024]
#define OFF_FLAG  13618836     // u32

__global__ void detect_kernel(const u32* __restrict__ xw, u32* __restrict__ flag) {
    __shared__ int cnt;
    if (threadIdx.x == 0) cnt = 0;
    __syncthreads();
    int hits = 0;
    for (int i = threadIdx.x; i < 1024; i += 256) {
        float v = bf2f((u16)(xw[i] & 0xffffu));
        if (!(fabsf(v) < 1e10f)) hits++;
    }
    atomicAdd(&cnt, hits);
    __syncthreads();
    if (threadIdx.x == 0) flag[0] = (cnt >= 16) ? 1u : 0u;
}

#define XBASE 26688
// setup: weight prep + bf16-pack x into xb
__global__ __launch_bounds__(256) void setup_kernel(
        const void* __restrict__ W_conv, const void* __restrict__ b_conv,
        const void* __restrict__ W_mix,  const void* __restrict__ b_mix,
        const void* __restrict__ W_ih,   const void* __restrict__ W_hh,
        const void* __restrict__ x,
        float* __restrict__ bcomb, u16* __restrict__ Wihb, u16* __restrict__ Whhb,
        u16* __restrict__ Wcb, u32* __restrict__ xb, const u32* __restrict__ flag) {
    int isf = (int)flag[0];
    int gid = blockIdx.x * 256 + threadIdx.x;
    if (gid < 12288) {
        Wihb[gid] = ldb(W_ih, gid, isf);
    } else if (gid < 24576) {
        int i = gid - 12288;
        Whhb[i] = ldb(W_hh, i, isf);
    } else if (gid < 26624) {
        int i = gid - 24576;
        int j = i >> 5, k = i & 31;
        int t0 = k >> 4, kk = k & 15;
        float acc = 0.f;
        for (int c = 0; c < 64; c++)
            acc += ldv(W_conv, (t0 * 16 + kk) * 64 + c, isf) * ldv(W_mix, (t0 * 64 + c) * 64 + j, isf);
        Wcb[i] = f2bf(acc);
    } else if (gid < XBASE) {
        int j = gid - 26624;
        if (j < 64) {
            float acc = ldv(b_mix, j, isf);
            for (int c = 0; c < 128; c++)
                acc += ldv(b_conv, c, isf) * ldv(W_mix, c * 64 + j, isf);
            bcomb[j] = acc;
        }
    } else if (gid < XBASE + NN * 8) {
        int i = gid - XBASE;
        int n = i >> 3, c = i & 7;
        u16 lo = ldb(x, (long)n * 16 + 2 * c, isf);
        u16 hi = ldb(x, (long)n * 16 + 2 * c + 1, isf);
        xb[i] = (u32)lo | ((u32)hi << 16);
    }
}

// per-block LDS histogram of coarse bucket ids (both sides)
__global__ __launch_bounds__(512) void countK(const int* __restrict__ en, const int* __restrict__ eh,
                                              const int* __restrict__ ea,
                                              int* __restrict__ cnts1, int* __restrict__ cnts2) {
    __shared__ int c1[NBK1], c2[NBK2];
    int blk = blockIdx.x, tid = threadIdx.x;
    for (int i = tid; i < NBK1; i += 512) c1[i] = 0;
    for (int i = tid; i < NBK2; i += 512) c2[i] = 0;
    __syncthreads();
    int s = blk * CHK;
    int e = s + CHK < EE ? s + CHK : EE;
    for (int i = s + tid; i < e; i += 512) {
        int t = ea[i];
        atomicAdd(&c1[(t * MHE + eh[i]) >> 8], 1);
        atomicAdd(&c2[(t * NN + en[i]) >> 8], 1);
    }
    __syncthreads();
    for (int b = tid; b < NBK1; b += 512) cnts1[b * NCB + blk] = c1[b];
    for (int b = tid; b < NBK2; b += 512) cnts2[b * NCB + blk] = c2[b];
}

__global__ __launch_bounds__(256) void scanP1(int* __restrict__ cnts1, int* __restrict__ cnts2,
                                              int* __restrict__ totals) {
    __shared__ int lds[256];
    int g = blockIdx.x, t = threadIdx.x;
    int* base = (g < NBK1) ? (cnts1 + (long)g * NCB) : (cnts2 + (long)(g - NBK1) * NCB);
    int v[4]; int s = 0;
    #pragma unroll
    for (int j = 0; j < 4; j++) { v[j] = base[t * 4 + j]; s += v[j]; }
    lds[t] = s;
    __syncthreads();
    for (int d = 1; d < 256; d <<= 1) {
        int tmp = (t >= d) ? lds[t - d] : 0;
        __syncthreads();
        lds[t] += tmp;
        __syncthreads();
    }
    int run = lds[t] - s;
    #pragma unroll
    for (int j = 0; j < 4; j++) { base[t * 4 + j] = run; run += v[j]; }
    if (t == 255) totals[g] = lds[255];
}

// parallel exclusive scan of the NGB bucket totals (single 1024-thread block)
__global__ __launch_bounds__(1024) void scanP2(const int* __restrict__ totals,
                                               int* __restrict__ bb1, int* __restrict__ bb2) {
    __shared__ int lds[1024];
    __shared__ int base2;
    int t = threadIdx.x;
    int v[3]; int s = 0;
    #pragma unroll
    for (int j = 0; j < 3; j++) {
        int idx = t * 3 + j;
        v[j] = (idx < NGB) ? totals[idx] : 0;
        s += v[j];
    }
    lds[t] = s;
    __syncthreads();
    for (int d = 1; d < 1024; d <<= 1) {
        int tmp = (t >= d) ? lds[t - d] : 0;
        __syncthreads();
        lds[t] += tmp;
        __syncthreads();
    }
    int run = lds[t] - s;
    int r = run;
    #pragma unroll
    for (int j = 0; j < 3; j++) {
        int idx = t * 3 + j;
        if (idx == NBK1) base2 = r;
        if (idx <= NBK1) bb1[idx] = r;
        r += v[j];
    }
    __syncthreads();
    r = run;
    #pragma unroll
    for (int j = 0; j < 3; j++) {
        int idx = t * 3 + j;
        if (idx >= NBK1 && idx <= NGB) bb2[idx - NBK1] = r - base2;
        r += v[j];
    }
}

__global__ __launch_bounds__(256) void scanP3(int* __restrict__ cnts1, int* __restrict__ cnts2,
                                              const int* __restrict__ bb1, const int* __restrict__ bb2) {
    int g = blockIdx.x, t = threadIdx.x;
    int add; int* base;
    if (g < NBK1) { base = cnts1 + (long)g * NCB; add = bb1[g]; }
    else          { base = cnts2 + (long)(g - NBK1) * NCB; add = bb2[g - NBK1]; }
    #pragma unroll
    for (int j = 0; j < 4; j++) base[t * 4 + j] += add;
}

// place packed payloads into bucket segments; ranks via LDS atomics
__global__ __launch_bounds__(1024) void placeK(const int* __restrict__ en, const int* __restrict__ eh,
                                               const int* __restrict__ ea,
                                               const int* __restrict__ cnts1, const int* __restrict__ cnts2,
                                               u32* __restrict__ bkt1, u32* __restrict__ bkt2) {
    __shared__ int r1[NBK1], r2[NBK2];
    int blk = blockIdx.x, tid = threadIdx.x;
    for (int i = tid; i < NBK1; i += 1024) r1[i] = 0;
    for (int i = tid; i < NBK2; i += 1024) r2[i] = 0;
    __syncthreads();
    int s = blk * CHK;
    int e = s + CHK < EE ? s + CHK : EE;
    for (int i = s + tid; i < e; i += 1024) {
        int t = ea[i]; int n = en[i];
        int k1 = t * MHE + eh[i];
        int k2 = t * NN + n;
        int b1 = k1 >> 8, b2 = k2 >> 8;
        int s1 = cnts1[b1 * NCB + blk] + atomicAdd(&r1[b1], 1);
        int s2 = cnts2[b2 * NCB + blk] + atomicAdd(&r2[b2], 1);
        bkt1[s1] = ((u32)(k1 & 255) << 17) | (u32)n;
        bkt2[s2] = ((u32)(k2 & 255) << 19) | (u32)k1;
    }
}

// hedge-side accumulation: 8-lane groups, bf16 x gathers, f32 LDS tile, bf16 exb out
__global__ __launch_bounds__(1024) void accumA(const u32* __restrict__ bkt1, const int* __restrict__ bb1,
                                               const u32* __restrict__ xb, u32* __restrict__ exb) {
    __shared__ float exl[256 * 16];
    __shared__ float bd[256];
    int b = blockIdx.x, tid = threadIdx.x;
    for (int i = tid; i < 256 * 16; i += 1024) exl[i] = 0.f;
    if (tid < 256) bd[tid] = 0.f;
    __syncthreads();
    int beg = bb1[b], end = bb1[b + 1];
    int sub = tid & 7, grp = tid >> 3;            // 128 groups
    int i = beg + grp;
    for (; i + 384 < end; i += 512) {
        u32 p0 = bkt1[i], p1 = bkt1[i + 128], p2 = bkt1[i + 256], p3 = bkt1[i + 384];
        u32 w0 = xb[(long)(p0 & 0x1FFFFu) * 8 + sub];
        u32 w1 = xb[(long)(p1 & 0x1FFFFu) * 8 + sub];
        u32 w2 = xb[(long)(p2 & 0x1FFFFu) * 8 + sub];
        u32 w3 = xb[(long)(p3 & 0x1FFFFu) * 8 + sub];
        int l0 = p0 >> 17, l1 = p1 >> 17, l2 = p2 >> 17, l3 = p3 >> 17;
        atomicAdd(&exl[l0 * 16 + 2 * sub],     bf2f((u16)(w0 & 0xffffu)));
        atomicAdd(&exl[l0 * 16 + 2 * sub + 1], bf2f((u16)(w0 >> 16)));
        atomicAdd(&exl[l1 * 16 + 2 * sub],     bf2f((u16)(w1 & 0xffffu)));
        atomicAdd(&exl[l1 * 16 + 2 * sub + 1], bf2f((u16)(w1 >> 16)));
        atomicAdd(&exl[l2 * 16 + 2 * sub],     bf2f((u16)(w2 & 0xffffu)));
        atomicAdd(&exl[l2 * 16 + 2 * sub + 1], bf2f((u16)(w2 >> 16)));
        atomicAdd(&exl[l3 * 16 + 2 * sub],     bf2f((u16)(w3 & 0xffffu)));
        atomicAdd(&exl[l3 * 16 + 2 * sub + 1], bf2f((u16)(w3 >> 16)));
        if (sub == 0) {
            atomicAdd(&bd[l0], 1.0f); atomicAdd(&bd[l1], 1.0f);
            atomicAdd(&bd[l2], 1.0f); atomicAdd(&bd[l3], 1.0f);
        }
    }
    for (; i < end; i += 128) {
        u32 p = bkt1[i];
        u32 w = xb[(long)(p & 0x1FFFFu) * 8 + sub];
        int l = p >> 17;
        atomicAdd(&exl[l * 16 + 2 * sub],     bf2f((u16)(w & 0xffffu)));
        atomicAdd(&exl[l * 16 + 2 * sub + 1], bf2f((u16)(w >> 16)));
        if (sub == 0) atomicAdd(&bd[l], 1.0f);
    }
    __syncthreads();
    for (int j = tid; j < 256 * 8; j += 1024) {     // pack 2 features per u32
        int k = j >> 3, c = j & 7;
        int key = b * 256 + k;
        if (key < H1) {
            float d = bd[k];
            float inv = d > 0.f ? 1.0f / d : 0.f;
            u16 lo = f2bf(exl[k * 16 + 2 * c] * inv);
            u16 hi = f2bf(exl[k * 16 + 2 * c + 1] * inv);
            exb[(long)key * 8 + c] = (u32)lo | ((u32)hi << 16);
        }
    }
}

// node-side accumulation: 8-lane groups, bf16 exb gathers, f32 LDS tile, f32 agg16 out
__global__ __launch_bounds__(1024) void accumB(const u32* __restrict__ bkt2, const int* __restrict__ bb2,
                                               const u32* __restrict__ exb, float* __restrict__ agg16) {
    __shared__ float agl[256 * 16];
    __shared__ float dd[256];
    int b = blockIdx.x, tid = threadIdx.x;
    for (int i = tid; i < 256 * 16; i += 1024) agl[i] = 0.f;
    if (tid < 256) dd[tid] = 0.f;
    __syncthreads();
    int beg = bb2[b], end = bb2[b + 1];
    int sub = tid & 7, grp = tid >> 3;
    int i = beg + grp;
    for (; i + 384 < end; i += 512) {
        u32 p0 = bkt2[i], p1 = bkt2[i + 128], p2 = bkt2[i + 256], p3 = bkt2[i + 384];
        u32 w0 = exb[(long)(p0 & 0x7FFFFu) * 8 + sub];
        u32 w1 = exb[(long)(p1 & 0x7FFFFu) * 8 + sub];
        u32 w2 = exb[(long)(p2 & 0x7FFFFu) * 8 + sub];
        u32 w3 = exb[(long)(p3 & 0x7FFFFu) * 8 + sub];
        int l0 = p0 >> 19, l1 = p1 >> 19, l2 = p2 >> 19, l3 = p3 >> 19;
        atomicAdd(&agl[l0 * 16 + 2 * sub],     bf2f((u16)(w0 & 0xffffu)));
        atomicAdd(&agl[l0 * 16 + 2 * sub + 1], bf2f((u16)(w0 >> 16)));
        atomicAdd(&agl[l1 * 16 + 2 * sub],     bf2f((u16)(w1 & 0xffffu)));
        atomicAdd(&agl[l1 * 16 + 2 * sub + 1], bf2f((u16)(w1 >> 16)));
        atomicAdd(&agl[l2 * 16 + 2 * sub],     bf2f((u16)(w2 & 0xffffu)));
        atomicAdd(&agl[l2 * 16 + 2 * sub + 1], bf2f((u16)(w2 >> 16)));
        atomicAdd(&agl[l3 * 16 + 2 * sub],     bf2f((u16)(w3 & 0xffffu)));
        atomicAdd(&agl[l3 * 16 + 2 * sub + 1], bf2f((u16)(w3 >> 16)));
        if (sub == 0) {
            atomicAdd(&dd[l0], 1.0f); atomicAdd(&dd[l1], 1.0f);
            atomicAdd(&dd[l2], 1.0f); atomicAdd(&dd[l3], 1.0f);
        }
    }
    for (; i < end; i += 128) {
        u32 p = bkt2[i];
        u32 w = exb[(long)(p & 0x7FFFFu) * 8 + sub];
        int l = p >> 19;
        atomicAdd(&agl[l * 16 + 2 * sub],     bf2f((u16)(w & 0xffffu)));
        atomicAdd(&agl[l * 16 + 2 * sub + 1], bf2f((u16)(w >> 16)));
        if (sub == 0) atomicAdd(&dd[l], 1.0f);
    }
    __syncthreads();
    for (int j = tid; j < 256 * 16; j += 1024) {
        int k = j >> 4;
        int key = b * 256 + k;
        if (key < H2) {
            float d = dd[k];
            agg16[(long)key * 16 + (j & 15)] = d > 0.f ? agl[j] * (1.0f / d) : 0.f;
        }
    }
}

// MFMA epilogue; agg16 pre-scaled by Binv and Dinv. (unchanged, passing since R7)
__global__ __launch_bounds__(256) void epilogue(const float* __restrict__ agg16,
                                                const float* __restrict__ bcomb,
                                                const u16* __restrict__ Wihb,
                                                const u16* __restrict__ Whhb,
                                                const u16* __restrict__ Wcb,
                                                const void* __restrict__ b_ih, const void* __restrict__ b_hh,
                                                const void* __restrict__ h_prev,
                                                const void* __restrict__ W_out, const void* __restrict__ b_out,
                                                void* __restrict__ out,
                                                const u32* __restrict__ flag) {
    __shared__ u16 hA[4][16][72];
    int isf = (int)flag[0];
    int tid = threadIdx.x;
    int w = tid >> 6, lane = tid & 63;
    int cl = lane & 15, q = lane >> 4;
    u16* hAw = &hA[w][0][0];

    float bcj[4], br[4], bz[4], bin_[4], bhn[4], wo0[4], wo1[4], wo2[4];
    #pragma unroll
    for (int c = 0; c < 4; c++) {
        int j = c * 16 + cl;
        bcj[c]  = bcomb[j];
        br[c]   = ldv(b_ih, j, isf)       + ldv(b_hh, j, isf);
        bz[c]   = ldv(b_ih, 64 + j, isf)  + ldv(b_hh, 64 + j, isf);
        bin_[c] = ldv(b_ih, 128 + j, isf);
        bhn[c]  = ldv(b_hh, 128 + j, isf);
        wo0[c]  = ldv(W_out, (long)j * 64 + 0, isf);
        wo1[c]  = ldv(W_out, (long)j * 64 + 1, isf);
        wo2[c]  = ldv(W_out, (long)j * 64 + 2, isf);
    }
    float bo0 = ldv(b_out, 0, isf), bo1 = ldv(b_out, 1, isf), bo2 = ldv(b_out, 2, isf);

    for (int wt = blockIdx.x * 4 + w; wt < NN / 16; wt += gridDim.x * 4) {
        long nb = (long)wt * 16;
        {
            int m = cl;
            int t0 = q >> 1;
            long nidx = nb + m;
            const float* ap = agg16 + ((long)t0 * NN + nidx) * 16 + (q & 1) * 8;
            f32x4 a0 = *(const f32x4*)ap;
            f32x4 a1 = *(const f32x4*)(ap + 4);
            FragU fa;
            fa.u[0]=f2bf(a0[0]); fa.u[1]=f2bf(a0[1]); fa.u[2]=f2bf(a0[2]); fa.u[3]=f2bf(a0[3]);
            fa.u[4]=f2bf(a1[0]); fa.u[5]=f2bf(a1[1]); fa.u[6]=f2bf(a1[2]); fa.u[7]=f2bf(a1[3]);
            f32x4 hacc[4];
            #pragma unroll
            for (int c = 0; c < 4; c++) {
                hacc[c] = (f32x4){0.f, 0.f, 0.f, 0.f};
                s16x8 bfr = *(const s16x8*)(Wcb + (c * 16 + cl) * 32 + q * 8);
                hacc[c] = __builtin_amdgcn_mfma_f32_16x16x32_bf16(fa.v, bfr, hacc[c], 0, 0, 0);
            }
            #pragma unroll
            for (int c = 0; c < 4; c++) {
                #pragma unroll
                for (int reg = 0; reg < 4; reg++) {
                    int row = q * 4 + reg;
                    float hv = fmaxf(hacc[c][reg] + bcj[c], 0.f);
                    hAw[row * 72 + c * 16 + cl] = f2bf(hv);
                }
            }
        }
        asm volatile("" ::: "memory");
        int m = cl;
        const u16* hrow = hAw + m * 72;
        FragU ha0, ha1;
        #pragma unroll
        for (int j = 0; j < 8; j++) {
            ha0.u[j] = hrow[q * 8 + j];
            ha1.u[j] = hrow[32 + q * 8 + j];
        }
        s16x8 hp0 = ld8bf(h_prev, (nb + m) * 64 + q * 8, isf);
        s16x8 hp1 = ld8bf(h_prev, (nb + m) * 64 + 32 + q * 8, isf);

        f32x4 accr[4], accz[4], accin[4], acchn[4];
        #pragma unroll
        for (int c = 0; c < 4; c++) {
            accr[c]  = (f32x4){br[c], br[c], br[c], br[c]};
            accz[c]  = (f32x4){bz[c], bz[c], bz[c], bz[c]};
            accin[c] = (f32x4){bin_[c], bin_[c], bin_[c], bin_[c]};
            acchn[c] = (f32x4){bhn[c], bhn[c], bhn[c], bhn[c]};
        }
        #pragma unroll
        for (int s = 0; s < 2; s++) {
            s16x8 hf  = s ? ha1.v : ha0.v;
            s16x8 hpf = s ? hp1 : hp0;
            int ko = s * 32 + q * 8;
            #pragma unroll
            for (int c = 0; c < 4; c++) {
                int rr = c * 16 + cl;
                s16x8 bir  = *(const s16x8*)(Wihb + (long)rr * 64 + ko);
                s16x8 bhr  = *(const s16x8*)(Whhb + (long)rr * 64 + ko);
                s16x8 biz  = *(const s16x8*)(Wihb + (long)(64 + rr) * 64 + ko);
                s16x8 bhz  = *(const s16x8*)(Whhb + (long)(64 + rr) * 64 + ko);
                s16x8 bin2 = *(const s16x8*)(Wihb + (long)(128 + rr) * 64 + ko);
                s16x8 bhn2 = *(const s16x8*)(Whhb + (long)(128 + rr) * 64 + ko);
                accr[c]  = __builtin_amdgcn_mfma_f32_16x16x32_bf16(hf,  bir, accr[c], 0, 0, 0);
                accr[c]  = __builtin_amdgcn_mfma_f32_16x16x32_bf16(hpf, bhr, accr[c], 0, 0, 0);
                accz[c]  = __builtin_amdgcn_mfma_f32_16x16x32_bf16(hf,  biz, accz[c], 0, 0, 0);
                accz[c]  = __builtin_amdgcn_mfma_f32_16x16x32_bf16(hpf, bhz, accz[c], 0, 0, 0);
                accin[c] = __builtin_amdgcn_mfma_f32_16x16x32_bf16(hf,  bin2, accin[c], 0, 0, 0);
                acchn[c] = __builtin_amdgcn_mfma_f32_16x16x32_bf16(hpf, bhn2, acchn[c], 0, 0, 0);
            }
        }
        float p0[4] = {0,0,0,0}, p1[4] = {0,0,0,0}, p2[4] = {0,0,0,0};
        #pragma unroll
        for (int c = 0; c < 4; c++) {
            #pragma unroll
            for (int reg = 0; reg < 4; reg++) {
                float rr = sigm(accr[c][reg]);
                float zz = sigm(accz[c][reg]);
                float ng = tanhf(accin[c][reg] + rr * acchn[c][reg]);
                long n = nb + q * 4 + reg;
                long j = c * 16 + cl;
                float hp = ldv(h_prev, n * 64 + j, isf);
                float hx = (1.f - zz) * ng + zz * hp;
                stv(out, n * 64 + j, hx, isf);
                p0[reg] += hx * wo0[c];
                p1[reg] += hx * wo1[c];
                p2[reg] += hx * wo2[c];
            }
        }
        #pragma unroll
        for (int reg = 0; reg < 4; reg++) {
            #pragma unroll
            for (int off2 = 1; off2 < 16; off2 <<= 1) {
                p0[reg] += __shfl_xor(p0[reg], off2);
                p1[reg] += __shfl_xor(p1[reg], off2);
                p2[reg] += __shfl_xor(p2[reg], off2);
            }
        }
        if (cl == 0) {
            #pragma unroll
            for (int reg = 0; reg < 4; reg++) {
                long n = nb + q * 4 + reg;
                long pb = (long)NN * 64 + n * 3;
                stv(out, pb + 0, p0[reg] + bo0, isf);
                stv(out, pb + 1, p1[reg] + bo1, isf);
                stv(out, pb + 2, p2[reg] + bo2, isf);
            }
        }
    }
}

extern "C" void kernel_launch(void* const* d_in, const int* in_sizes, int n_in,
                              void* d_out, int out_size, void* d_ws, size_t ws_size,
                              hipStream_t stream) {
    const void* x      = d_in[0];
    const void* h_prev = d_in[1];
    const int* en      = (const int*)d_in[2];
    const int* eh      = (const int*)d_in[3];
    const int* ea      = (const int*)d_in[4];
    const void* W_conv = d_in[5];
    const void* b_conv = d_in[6];
    const void* W_mix  = d_in[7];
    const void* b_mix  = d_in[8];
    const void* W_ih   = d_in[9];
    const void* W_hh   = d_in[10];
    const void* b_ih   = d_in[11];
    const void* b_hh   = d_in[12];
    const void* W_out  = d_in[13];
    const void* b_out  = d_in[14];
    void* out          = d_out;

    float* ws    = (float*)d_ws;
    u32* bkt1    = (u32*)(ws + OFF_BKT1);
    u32* bkt2    = (u32*)(ws + OFF_BKT2);
    u32* exb     = (u32*)(ws + OFF_EXB);
    float* agg16 = ws + OFF_AGG;
    u32* xb      = (u32*)(ws + OFF_XB);
    int* cnts1   = (int*)(ws + OFF_CNT1);
    int* cnts2   = (int*)(ws + OFF_CNT2);
    int* totals  = (int*)(ws + OFF_TOT);
    int* bb1     = (int*)(ws + OFF_BB1);
    int* bb2     = (int*)(ws + OFF_BB2);
    float* bcomb = ws + OFF_BCOMB;
    u16* Wihb    = (u16*)(ws + OFF_WIHB);
    u16* Whhb    = (u16*)(ws + OFF_WHHB);
    u16* Wcb     = (u16*)(ws + OFF_WCB);
    u32* flag    = (u32*)(ws + OFF_FLAG);

    detect_kernel<<<1, 256, 0, stream>>>((const u32*)x, flag);
    setup_kernel<<<(XBASE + NN * 8 + 255) / 256, 256, 0, stream>>>(
        W_conv, b_conv, W_mix, b_mix, W_ih, W_hh, x,
        bcomb, Wihb, Whhb, Wcb, xb, flag);
    countK<<<NCB, 512, 0, stream>>>(en, eh, ea, cnts1, cnts2);
    scanP1<<<NGB, 256, 0, stream>>>(cnts1, cnts2, totals);
    scanP2<<<1, 1024, 0, stream>>>(totals, bb1, bb2);
    scanP3<<<NGB, 256, 0, stream>>>(cnts1, cnts2, bb1, bb2);
    placeK<<<NCB, 1024, 0, stream>>>(en, eh, ea, cnts1, cnts2, bkt1, bkt2);
    accumA<<<NBK1, 1024, 0, stream>>>(bkt1, bb1, xb, exb);
    accumB<<<NBK2, 1024, 0, stream>>>(bkt2, bb2, exb, agg16);
    epilogue<<<1563, 256, 0, stream>>>(agg16, bcomb, Wihb, Whhb, Wcb,
                                       b_ih, b_hh, h_prev, W_out, b_out, out, flag);
}

// Round 11
// 603.491 us; speedup vs baseline: 1.3722x; 1.2796x over previous
//
#include <hip/hip_runtime.h>

#define NN      100000
#define MHE     200000
#define EE      2000000
#define H1      400000      // hedge keys (2 types)
#define NBK1    782         // ceil(H1/512)
#define NCB     1024        // counting blocks
#define CHK     1954        // edges per counting block

typedef unsigned short u16;
typedef unsigned int   u32;
typedef unsigned long long ull;
typedef __attribute__((ext_vector_type(8))) short  s16x8;
typedef __attribute__((ext_vector_type(2))) short  s16x2;
typedef __attribute__((ext_vector_type(4))) float  f32x4;
typedef __attribute__((ext_vector_type(4))) unsigned int u32x4;

__device__ __forceinline__ float bf2f(u16 u) { return __uint_as_float(((u32)u) << 16); }
__device__ __forceinline__ u16 f2bf(float f) {
    u32 u = __float_as_uint(f);
    return (u16)((u + 0x7fffu + ((u >> 16) & 1u)) >> 16);
}
__device__ __forceinline__ float ldv(const void* p, long i, int isf32) {
    return isf32 ? ((const float*)p)[i] : bf2f(((const u16*)p)[i]);
}
__device__ __forceinline__ u16 ldb(const void* p, long i, int isf32) {
    return isf32 ? f2bf(((const float*)p)[i]) : ((const u16*)p)[i];
}
__device__ __forceinline__ void stv(void* p, long i, float v, int isf32) {
    if (isf32) ((float*)p)[i] = v;
    else       ((u16*)p)[i] = f2bf(v);
}

// packed bf16x2 global atomic add (HW on gfx940+; CAS fallback otherwise)
__device__ __forceinline__ void pkAddBf16(u32* addr, u32 val) {
#if __has_builtin(__builtin_amdgcn_flat_atomic_fadd_v2bf16)
    union { u32 u; s16x2 s; } c; c.u = val;
    __builtin_amdgcn_flat_atomic_fadd_v2bf16((s16x2*)addr, c.s);
#else
    u32 old = __atomic_load_n(addr, __ATOMIC_RELAXED), assumed;
    do {
        assumed = old;
        float lo = bf2f((u16)(assumed & 0xffffu)) + bf2f((u16)(val & 0xffffu));
        float hi = bf2f((u16)(assumed >> 16))     + bf2f((u16)(val >> 16));
        u32 nv = (u32)f2bf(lo) | ((u32)f2bf(hi) << 16);
        old = atomicCAS(addr, assumed, nv);
    } while (old != assumed);
#endif
}

union FragU { s16x8 v; ull q[2]; u16 u[8]; };

__device__ __forceinline__ s16x8 ld8bf(const void* p, long off, int isf32) {
    FragU f;
    if (isf32) {
        const float* fp = (const float*)p + off;
        f32x4 a = *(const f32x4*)fp;
        f32x4 b = *(const f32x4*)(fp + 4);
        f.u[0]=f2bf(a[0]); f.u[1]=f2bf(a[1]); f.u[2]=f2bf(a[2]); f.u[3]=f2bf(a[3]);
        f.u[4]=f2bf(b[0]); f.u[5]=f2bf(b[1]); f.u[6]=f2bf(b[2]); f.u[7]=f2bf(b[3]);
    } else {
        u32x4 w = *(const u32x4*)((const u16*)p + off);
        f.q[0] = ((ull)w[1] << 32) | w[0];
        f.q[1] = ((ull)w[3] << 32) | w[2];
    }
    return f.v;
}

__device__ __forceinline__ float sigm(float x) { return 1.f / (1.f + __expf(-x)); }

// ---- ws layout (4-byte units) ----
#define OFF_BKT1  0            // u32[2,000,000]
#define OFF_AGGB  2000000      // u32[1,600,000]  aggb [2][NN][8] bf16-pairs (zeroed)
#define OFF_DDEG  3600000      // f32[200,000]    (zeroed)
#define OFF_XB    3800000      // u32[800,000]    xb [NN][8] bf16-pairs
#define OFF_CNT1  4600000      // int[NBK1*NCB = 800,768]
#define OFF_TOT   5400768      // int[NBK1]
#define OFF_BB1   5401550      // int[NBK1+1]
#define OFF_BCOMB 5402333      // f32[64]
#define OFF_WIHB  5402397      // u16[12288]
#define OFF_WHHB  5408541      // u16[12288]
#define OFF_WCB   5414685      // u16[1024]
#define OFF_FLAG  5415197      // u32

__global__ void detect_kernel(const u32* __restrict__ xw, u32* __restrict__ flag) {
    __shared__ int cnt;
    if (threadIdx.x == 0) cnt = 0;
    __syncthreads();
    int hits = 0;
    for (int i = threadIdx.x; i < 1024; i += 256) {
        float v = bf2f((u16)(xw[i] & 0xffffu));
        if (!(fabsf(v) < 1e10f)) hits++;
    }
    atomicAdd(&cnt, hits);
    __syncthreads();
    if (threadIdx.x == 0) flag[0] = (cnt >= 16) ? 1u : 0u;
}

#define XBASE 26688
__global__ __launch_bounds__(256) void setup_kernel(
        const void* __restrict__ W_conv, const void* __restrict__ b_conv,
        const void* __restrict__ W_mix,  const void* __restrict__ b_mix,
        const void* __restrict__ W_ih,   const void* __restrict__ W_hh,
        const void* __restrict__ x,
        float* __restrict__ bcomb, u16* __restrict__ Wihb, u16* __restrict__ Whhb,
        u16* __restrict__ Wcb, u32* __restrict__ xb, const u32* __restrict__ flag) {
    int isf = (int)flag[0];
    int gid = blockIdx.x * 256 + threadIdx.x;
    if (gid < 12288) {
        Wihb[gid] = ldb(W_ih, gid, isf);
    } else if (gid < 24576) {
        int i = gid - 12288;
        Whhb[i] = ldb(W_hh, i, isf);
    } else if (gid < 26624) {
        int i = gid - 24576;
        int j = i >> 5, k = i & 31;
        int t0 = k >> 4, kk = k & 15;
        float acc = 0.f;
        for (int c = 0; c < 64; c++)
            acc += ldv(W_conv, (t0 * 16 + kk) * 64 + c, isf) * ldv(W_mix, (t0 * 64 + c) * 64 + j, isf);
        Wcb[i] = f2bf(acc);
    } else if (gid < XBASE) {
        int j = gid - 26624;
        if (j < 64) {
            float acc = ldv(b_mix, j, isf);
            for (int c = 0; c < 128; c++)
                acc += ldv(b_conv, c, isf) * ldv(W_mix, c * 64 + j, isf);
            bcomb[j] = acc;
        }
    } else if (gid < XBASE + NN * 8) {
        int i = gid - XBASE;
        int n = i >> 3, c = i & 7;
        u16 lo = ldb(x, (long)n * 16 + 2 * c, isf);
        u16 hi = ldb(x, (long)n * 16 + 2 * c + 1, isf);
        xb[i] = (u32)lo | ((u32)hi << 16);
    }
}

// hedge-side bucket histogram only
__global__ __launch_bounds__(512) void countK1(const int* __restrict__ eh, const int* __restrict__ ea,
                                               int* __restrict__ cnts1) {
    __shared__ int c1[NBK1];
    int blk = blockIdx.x, tid = threadIdx.x;
    for (int i = tid; i < NBK1; i += 512) c1[i] = 0;
    __syncthreads();
    int s = blk * CHK;
    int e = s + CHK < EE ? s + CHK : EE;
    for (int i = s + tid; i < e; i += 512)
        atomicAdd(&c1[(ea[i] * MHE + eh[i]) >> 9], 1);
    __syncthreads();
    for (int b = tid; b < NBK1; b += 512) cnts1[b * NCB + blk] = c1[b];
}

__global__ __launch_bounds__(256) void scanP1(int* __restrict__ cnts1, int* __restrict__ totals) {
    __shared__ int lds[256];
    int g = blockIdx.x, t = threadIdx.x;
    int* base = cnts1 + (long)g * NCB;
    int v[4]; int s = 0;
    #pragma unroll
    for (int j = 0; j < 4; j++) { v[j] = base[t * 4 + j]; s += v[j]; }
    lds[t] = s;
    __syncthreads();
    for (int d = 1; d < 256; d <<= 1) {
        int tmp = (t >= d) ? lds[t - d] : 0;
        __syncthreads();
        lds[t] += tmp;
        __syncthreads();
    }
    int run = lds[t] - s;
    #pragma unroll
    for (int j = 0; j < 4; j++) { base[t * 4 + j] = run; run += v[j]; }
    if (t == 255) totals[g] = lds[255];
}

__global__ __launch_bounds__(1024) void scanP2(const int* __restrict__ totals, int* __restrict__ bb1) {
    __shared__ int lds[1024];
    int t = threadIdx.x;
    int v = (t < NBK1) ? totals[t] : 0;
    lds[t] = v;
    __syncthreads();
    for (int d = 1; d < 1024; d <<= 1) {
        int tmp = (t >= d) ? lds[t - d] : 0;
        __syncthreads();
        lds[t] += tmp;
        __syncthreads();
    }
    if (t < NBK1) bb1[t] = lds[t] - v;
    if (t == NBK1 - 1) bb1[NBK1] = lds[t];
}

__global__ __launch_bounds__(256) void scanP3(int* __restrict__ cnts1, const int* __restrict__ bb1) {
    int g = blockIdx.x, t = threadIdx.x;
    int* base = cnts1 + (long)g * NCB;
    int add = bb1[g];
    #pragma unroll
    for (int j = 0; j < 4; j++) base[t * 4 + j] += add;
}

// place (local-key, node) payloads into hedge-bucket segments
__global__ __launch_bounds__(1024) void placeK1(const int* __restrict__ en, const int* __restrict__ eh,
                                                const int* __restrict__ ea,
                                                const int* __restrict__ cnts1, u32* __restrict__ bkt1) {
    __shared__ int r1[NBK1];
    int blk = blockIdx.x, tid = threadIdx.x;
    for (int i = tid; i < NBK1; i += 1024) r1[i] = 0;
    __syncthreads();
    int s = blk * CHK;
    int e = s + CHK < EE ? s + CHK : EE;
    for (int i = s + tid; i < e; i += 1024) {
        int k1 = ea[i] * MHE + eh[i];
        int b1 = k1 >> 9;
        int s1 = cnts1[b1 * NCB + blk] + atomicAdd(&r1[b1], 1);
        bkt1[s1] = ((u32)(k1 & 511) << 17) | (u32)en[i];
    }
}

// FUSED hop1 + hop2: build 512-hedge ex tile in LDS (Binv folded), then scatter
// packed-bf16 rows into aggb with pk atomics. exb never materialized.
__global__ __launch_bounds__(1024) void accumAB(const u32* __restrict__ bkt1, const int* __restrict__ bb1,
                                                const u32* __restrict__ xb,
                                                u32* __restrict__ aggb, float* __restrict__ Ddeg) {
    __shared__ float exl[512 * 16];   // 32 KB
    __shared__ float bd[512];
    __shared__ u32  exp_[512 * 8];    // 16 KB packed bf16 rows
    int b = blockIdx.x, tid = threadIdx.x;
    for (int i = tid; i < 512 * 16; i += 1024) exl[i] = 0.f;
    if (tid < 512) bd[tid] = 0.f;
    __syncthreads();
    int beg = bb1[b], end = bb1[b + 1];
    int sub = tid & 7, grp = tid >> 3;            // 128 groups
    for (int i = beg + grp; i < end; i += 128) {
        u32 p = bkt1[i];
        int l = (int)(p >> 17), n = (int)(p & 0x1FFFFu);
        u32 w = xb[(long)n * 8 + sub];
        atomicAdd(&exl[l * 16 + 2 * sub],     bf2f((u16)(w & 0xffffu)));
        atomicAdd(&exl[l * 16 + 2 * sub + 1], bf2f((u16)(w >> 16)));
        if (sub == 0) atomicAdd(&bd[l], 1.0f);
    }
    __syncthreads();
    // Binv + pack
    for (int j = tid; j < 512 * 8; j += 1024) {
        int k = j >> 3, c = j & 7;
        float d = bd[k];
        float inv = d > 0.f ? 1.0f / d : 0.f;
        u16 lo = f2bf(exl[k * 16 + 2 * c] * inv);
        u16 hi = f2bf(exl[k * 16 + 2 * c + 1] * inv);
        exp_[j] = (u32)lo | ((u32)hi << 16);
    }
    __syncthreads();
    // hop-2 scatter: aggb[t][node] += ex row (pk bf16 atomics), count Ddeg
    for (int i = beg + grp; i < end; i += 128) {
        u32 p = bkt1[i];
        int l = (int)(p >> 17), n = (int)(p & 0x1FFFFu);
        int key = b * 512 + l;
        int t = key >= MHE ? 1 : 0;
        u32 v = exp_[l * 8 + sub];
        pkAddBf16(aggb + ((long)t * NN + n) * 8 + sub, v);
        if (sub == 0) atomicAdd(Ddeg + (long)t * NN + n, 1.0f);
    }
}

// MFMA epilogue; stage-1 A = Dinv * aggb (bf16), rest unchanged (passing since R7)
__global__ __launch_bounds__(256) void epilogue(const u32* __restrict__ aggb,
                                                const float* __restrict__ Ddeg,
                                                const float* __restrict__ bcomb,
                                                const u16* __restrict__ Wihb,
                                                const u16* __restrict__ Whhb,
                                                const u16* __restrict__ Wcb,
                                                const void* __restrict__ b_ih, const void* __restrict__ b_hh,
                                                const void* __restrict__ h_prev,
                                                const void* __restrict__ W_out, const void* __restrict__ b_out,
                                                void* __restrict__ out,
                                                const u32* __restrict__ flag) {
    __shared__ u16 hA[4][16][72];
    int isf = (int)flag[0];
    int tid = threadIdx.x;
    int w = tid >> 6, lane = tid & 63;
    int cl = lane & 15, q = lane >> 4;
    u16* hAw = &hA[w][0][0];

    float bcj[4], br[4], bz[4], bin_[4], bhn[4], wo0[4], wo1[4], wo2[4];
    #pragma unroll
    for (int c = 0; c < 4; c++) {
        int j = c * 16 + cl;
        bcj[c]  = bcomb[j];
        br[c]   = ldv(b_ih, j, isf)       + ldv(b_hh, j, isf);
        bz[c]   = ldv(b_ih, 64 + j, isf)  + ldv(b_hh, 64 + j, isf);
        bin_[c] = ldv(b_ih, 128 + j, isf);
        bhn[c]  = ldv(b_hh, 128 + j, isf);
        wo0[c]  = ldv(W_out, (long)j * 64 + 0, isf);
        wo1[c]  = ldv(W_out, (long)j * 64 + 1, isf);
        wo2[c]  = ldv(W_out, (long)j * 64 + 2, isf);
    }
    float bo0 = ldv(b_out, 0, isf), bo1 = ldv(b_out, 1, isf), bo2 = ldv(b_out, 2, isf);

    for (int wt = blockIdx.x * 4 + w; wt < NN / 16; wt += gridDim.x * 4) {
        long nb = (long)wt * 16;
        {
            int m = cl;
            int t0 = q >> 1;
            long nidx = nb + m;
            const u32* ap = aggb + ((long)t0 * NN + nidx) * 8 + (q & 1) * 4;
            u32 a0 = ap[0], a1 = ap[1], a2 = ap[2], a3 = ap[3];
            float dd = Ddeg[(long)t0 * NN + nidx];
            float isc = dd > 0.f ? 1.0f / dd : 0.f;
            FragU fa;
            fa.u[0]=f2bf(bf2f((u16)(a0 & 0xffffu)) * isc); fa.u[1]=f2bf(bf2f((u16)(a0 >> 16)) * isc);
            fa.u[2]=f2bf(bf2f((u16)(a1 & 0xffffu)) * isc); fa.u[3]=f2bf(bf2f((u16)(a1 >> 16)) * isc);
            fa.u[4]=f2bf(bf2f((u16)(a2 & 0xffffu)) * isc); fa.u[5]=f2bf(bf2f((u16)(a2 >> 16)) * isc);
            fa.u[6]=f2bf(bf2f((u16)(a3 & 0xffffu)) * isc); fa.u[7]=f2bf(bf2f((u16)(a3 >> 16)) * isc);
            f32x4 hacc[4];
            #pragma unroll
            for (int c = 0; c < 4; c++) {
                hacc[c] = (f32x4){0.f, 0.f, 0.f, 0.f};
                s16x8 bfr = *(const s16x8*)(Wcb + (c * 16 + cl) * 32 + q * 8);
                hacc[c] = __builtin_amdgcn_mfma_f32_16x16x32_bf16(fa.v, bfr, hacc[c], 0, 0, 0);
            }
            #pragma unroll
            for (int c = 0; c < 4; c++) {
                #pragma unroll
                for (int reg = 0; reg < 4; reg++) {
                    int row = q * 4 + reg;
                    float hv = fmaxf(hacc[c][reg] + bcj[c], 0.f);
                    hAw[row * 72 + c * 16 + cl] = f2bf(hv);
                }
            }
        }
        asm volatile("" ::: "memory");
        int m = cl;
        const u16* hrow = hAw + m * 72;
        FragU ha0, ha1;
        #pragma unroll
        for (int j = 0; j < 8; j++) {
            ha0.u[j] = hrow[q * 8 + j];
            ha1.u[j] = hrow[32 + q * 8 + j];
        }
        s16x8 hp0 = ld8bf(h_prev, (nb + m) * 64 + q * 8, isf);
        s16x8 hp1 = ld8bf(h_prev, (nb + m) * 64 + 32 + q * 8, isf);

        f32x4 accr[4], accz[4], accin[4], acchn[4];
        #pragma unroll
        for (int c = 0; c < 4; c++) {
            accr[c]  = (f32x4){br[c], br[c], br[c], br[c]};
            accz[c]  = (f32x4){bz[c], bz[c], bz[c], bz[c]};
            accin[c] = (f32x4){bin_[c], bin_[c], bin_[c], bin_[c]};
            acchn[c] = (f32x4){bhn[c], bhn[c], bhn[c], bhn[c]};
        }
        #pragma unroll
        for (int s = 0; s < 2; s++) {
            s16x8 hf  = s ? ha1.v : ha0.v;
            s16x8 hpf = s ? hp1 : hp0;
            int ko = s * 32 + q * 8;
            #pragma unroll
            for (int c = 0; c < 4; c++) {
                int rr = c * 16 + cl;
                s16x8 bir  = *(const s16x8*)(Wihb + (long)rr * 64 + ko);
                s16x8 bhr  = *(const s16x8*)(Whhb + (long)rr * 64 + ko);
                s16x8 biz  = *(const s16x8*)(Wihb + (long)(64 + rr) * 64 + ko);
                s16x8 bhz  = *(const s16x8*)(Whhb + (long)(64 + rr) * 64 + ko);
                s16x8 bin2 = *(const s16x8*)(Wihb + (long)(128 + rr) * 64 + ko);
                s16x8 bhn2 = *(const s16x8*)(Whhb + (long)(128 + rr) * 64 + ko);
                accr[c]  = __builtin_amdgcn_mfma_f32_16x16x32_bf16(hf,  bir, accr[c], 0, 0, 0);
                accr[c]  = __builtin_amdgcn_mfma_f32_16x16x32_bf16(hpf, bhr, accr[c], 0, 0, 0);
                accz[c]  = __builtin_amdgcn_mfma_f32_16x16x32_bf16(hf,  biz, accz[c], 0, 0, 0);
                accz[c]  = __builtin_amdgcn_mfma_f32_16x16x32_bf16(hpf, bhz, accz[c], 0, 0, 0);
                accin[c] = __builtin_amdgcn_mfma_f32_16x16x32_bf16(hf,  bin2, accin[c], 0, 0, 0);
                acchn[c] = __builtin_amdgcn_mfma_f32_16x16x32_bf16(hpf, bhn2, acchn[c], 0, 0, 0);
            }
        }
        float p0[4] = {0,0,0,0}, p1[4] = {0,0,0,0}, p2[4] = {0,0,0,0};
        #pragma unroll
        for (int c = 0; c < 4; c++) {
            #pragma unroll
            for (int reg = 0; reg < 4; reg++) {
                float rr = sigm(accr[c][reg]);
                float zz = sigm(accz[c][reg]);
                float ng = tanhf(accin[c][reg] + rr * acchn[c][reg]);
                long n = nb + q * 4 + reg;
                long j = c * 16 + cl;
                float hp = ldv(h_prev, n * 64 + j, isf);
                float hx = (1.f - zz) * ng + zz * hp;
                stv(out, n * 64 + j, hx, isf);
                p0[reg] += hx * wo0[c];
                p1[reg] += hx * wo1[c];
                p2[reg] += hx * wo2[c];
            }
        }
        #pragma unroll
        for (int reg = 0; reg < 4; reg++) {
            #pragma unroll
            for (int off2 = 1; off2 < 16; off2 <<= 1) {
                p0[reg] += __shfl_xor(p0[reg], off2);
                p1[reg] += __shfl_xor(p1[reg], off2);
                p2[reg] += __shfl_xor(p2[reg], off2);
            }
        }
        if (cl == 0) {
            #pragma unroll
            for (int reg = 0; reg < 4; reg++) {
                long n = nb + q * 4 + reg;
                long pb = (long)NN * 64 + n * 3;
                stv(out, pb + 0, p0[reg] + bo0, isf);
                stv(out, pb + 1, p1[reg] + bo1, isf);
                stv(out, pb + 2, p2[reg] + bo2, isf);
            }
        }
    }
}

extern "C" void kernel_launch(void* const* d_in, const int* in_sizes, int n_in,
                              void* d_out, int out_size, void* d_ws, size_t ws_size,
                              hipStream_t stream) {
    const void* x      = d_in[0];
    const void* h_prev = d_in[1];
    const int* en      = (const int*)d_in[2];
    const int* eh      = (const int*)d_in[3];
    const int* ea      = (const int*)d_in[4];
    const void* W_conv = d_in[5];
    const void* b_conv = d_in[6];
    const void* W_mix  = d_in[7];
    const void* b_mix  = d_in[8];
    const void* W_ih   = d_in[9];
    const void* W_hh   = d_in[10];
    const void* b_ih   = d_in[11];
    const void* b_hh   = d_in[12];
    const void* W_out  = d_in[13];
    const void* b_out  = d_in[14];
    void* out          = d_out;

    float* ws    = (float*)d_ws;
    u32* bkt1    = (u32*)(ws + OFF_BKT1);
    u32* aggb    = (u32*)(ws + OFF_AGGB);
    float* Ddeg  = ws + OFF_DDEG;
    u32* xb      = (u32*)(ws + OFF_XB);
    int* cnts1   = (int*)(ws + OFF_CNT1);
    int* totals  = (int*)(ws + OFF_TOT);
    int* bb1     = (int*)(ws + OFF_BB1);
    float* bcomb = ws + OFF_BCOMB;
    u16* Wihb    = (u16*)(ws + OFF_WIHB);
    u16* Whhb    = (u16*)(ws + OFF_WHHB);
    u16* Wcb     = (u16*)(ws + OFF_WCB);
    u32* flag    = (u32*)(ws + OFF_FLAG);

    // zero aggb + Ddeg (contiguous 7.2 MB)
    (void)hipMemsetAsync(aggb, 0, (size_t)(1600000 + 200000) * 4, stream);
    detect_kernel<<<1, 256, 0, stream>>>((const u32*)x, flag);
    setup_kernel<<<(XBASE + NN * 8 + 255) / 256, 256, 0, stream>>>(
        W_conv, b_conv, W_mix, b_mix, W_ih, W_hh, x,
        bcomb, Wihb, Whhb, Wcb, xb, flag);
    countK1<<<NCB, 512, 0, stream>>>(eh, ea, cnts1);
    scanP1<<<NBK1, 256, 0, stream>>>(cnts1, totals);
    scanP2<<<1, 1024, 0, stream>>>(totals, bb1);
    scanP3<<<NBK1, 256, 0, stream>>>(cnts1, bb1);
    placeK1<<<NCB, 1024, 0, stream>>>(en, eh, ea, cnts1, bkt1);
    accumAB<<<NBK1, 1024, 0, stream>>>(bkt1, bb1, xb, aggb, Ddeg);
    epilogue<<<1563, 256, 0, stream>>>(aggb, Ddeg, bcomb, Wihb, Whhb, Wcb,
                                       b_ih, b_hh, h_prev, W_out, b_out, out, flag);
}